// Round 15
// baseline (8728.328 us; speedup 1.0000x reference)
//
#include <hip/hip_runtime.h>
#include <stdint.h>

typedef unsigned short u16;
typedef __attribute__((ext_vector_type(8))) short bf16x8;
typedef __attribute__((ext_vector_type(4))) float f32x4;
typedef __attribute__((ext_vector_type(4))) int   i32x4;
typedef __attribute__((ext_vector_type(4))) unsigned short u16x4;

#define DI static __device__ __forceinline__

constexpr int B_   = 64;
constexpr int TD   = 800;
constexpr int TC   = 80;
constexpr int ENC  = 128;
constexpr int H    = 400;
constexpr int OUTN = 121;

constexpr int HP   = 416;
constexpr int KT_H = 13;
constexpr int KOP  = 1216;
constexpr int NOP  = 128;
constexpr int NBL  = 25;
constexpr int NBA  = 32;
constexpr int CSTR = 32;
constexpr int FSLOT= 32;

// ---------------- workspace layout ----------------
constexpr size_t HB_B  = (size_t)(TD+1)*B_*HP*2;
constexpr size_t WBF_B = (size_t)TD*B_*ENC*2;
constexpr size_t STR_B = (size_t)TD*B_*4*4;
constexpr size_t APK_B = (size_t)NBL*4*KT_H*64*8*2;
constexpr size_t WF_B  = (size_t)NBL*4*17*64*8*2;
constexpr size_t LOC_B = (size_t)2*B_*HP*2;
constexpr size_t PIN_B = (size_t)2*B_*HP*2;     // staged h_prev (double buf)
constexpr size_t WIN_B = (size_t)2*B_*ENC*2;    // staged w (double buf)

constexpr size_t OFF_HB0 = 0;
constexpr size_t OFF_HB1 = OFF_HB0 + HB_B;
constexpr size_t OFF_HB2 = OFF_HB1 + HB_B;
constexpr size_t OFF_HLO = OFF_HB2 + HB_B;
constexpr size_t OFF_WBF = OFF_HLO + HB_B;
constexpr size_t OFF_STR = OFF_WBF + WBF_B;
constexpr size_t OFF_APKH= OFF_STR + STR_B;
constexpr size_t OFF_APKL= OFF_APKH + 3*APK_B;
constexpr size_t OFF_WF1 = OFF_APKL + APK_B;
constexpr size_t OFF_WF2 = OFF_WF1 + WF_B;
constexpr size_t OFF_OUW = OFF_WF2 + WF_B;
constexpr size_t OFF_BIA = OFF_OUW + (size_t)NOP*KOP*2;
constexpr size_t OFF_CNT = OFF_BIA + (size_t)3*1600*4;
constexpr size_t OFF_XCC = OFF_CNT + (size_t)4*FSLOT*CSTR*4;
constexpr size_t OFF_FLG = OFF_XCC + (size_t)3*FSLOT*CSTR*4;   // 5 slots: 3 self + 2 stage
constexpr size_t OFF_HL0 = OFF_FLG + (size_t)5*FSLOT*CSTR*4;
constexpr size_t OFF_LL0 = OFF_HL0 + LOC_B;
constexpr size_t OFF_HL1 = OFF_LL0 + LOC_B;
constexpr size_t OFF_HL2 = OFF_HL1 + LOC_B;
constexpr size_t OFF_PI1 = OFF_HL2 + LOC_B;
constexpr size_t OFF_WI1 = OFF_PI1 + PIN_B;
constexpr size_t OFF_PI2 = OFF_WI1 + WIN_B;
constexpr size_t OFF_WI2 = OFF_PI2 + PIN_B;
constexpr size_t WS_NEED = OFF_WI2 + WIN_B + 256;

// LDS offsets
constexpr int LDS_DUMP = 0;
constexpr int LDS_CL   = 66560;
constexpr int LDS_EX   = 70656;
constexpr int LDS_W3   = 140288;
constexpr int LDS_BIAS = 141056;
constexpr int LDS_VERD = 141312;
constexpr int LDSB     = 141568;
constexpr int ALDS_CTX = 0;
constexpr int ALDS_ATW = 81920;
constexpr int ALDS_H   = 130040;
constexpr int ALDS_PHI = 133240;
constexpr int ALDS_MSK = 133880;
constexpr int ALDS_KAP = 134520;
constexpr int ALDS_P   = 134600;
constexpr int ALDS_PPS = 134840;

DI u16 f2b(float f){ union{float f; unsigned u;} v; v.f=f; unsigned r = v.u + 0x7FFFu + ((v.u>>16)&1u); return (u16)(r>>16); }
DI float b2f(u16 h){ union{unsigned u; float f;} v; v.u=((unsigned)h)<<16; return v.f; }
DI float sigm(float x){ return 1.f/(1.f+__expf(-x)); }
DI float tanh_(float x){ float a=fabsf(x), e=__expf(-2.f*a), t=(1.f-e)/(1.f+e); return x<0.f ? -t : t; }

DI void st16(u16* p, u16 v){
  asm volatile("global_store_short %0, %1, off sc0 sc1" :: "v"(p), "v"((unsigned)v) : "memory");
}
DI void st8(u16* p, u16x4 v){
  unsigned long long x; __builtin_memcpy(&x, &v, 8);
  asm volatile("global_store_dwordx2 %0, %1, off sc0 sc1" :: "v"(p), "v"(x) : "memory");
}
DI void setflag(unsigned* p, unsigned t){
  asm volatile("global_store_dword %0, %1, off sc0 sc1" :: "v"(p), "v"(t) : "memory");
}
// LLC flag wait (relaxed gather)
DI void waitflags2(const unsigned* fA, int nA, unsigned tA,
                   const unsigned* fB, int nB, unsigned tB){
  int lane = threadIdx.x & 63;
  const unsigned* p; unsigned tgt;
  if (lane < nA)            { p = fA + (size_t)lane*CSTR;        tgt = tA; }
  else if (lane < nA+nB)    { p = fB + (size_t)(lane-nA)*CSTR;   tgt = tB; }
  else                      { p = fA;                            tgt = 0;  }
  while (1) {
    unsigned v = __hip_atomic_load(p, __ATOMIC_RELAXED, __HIP_MEMORY_SCOPE_AGENT);
    if (__all(v >= tgt)) break;
    __builtin_amdgcn_s_sleep(1);
  }
  asm volatile("" ::: "memory");
}
// XCD-local flag wait: volatile poll with light sleep
DI void waitloc(const unsigned* f, int n, unsigned tgt){
  int lane = threadIdx.x & 63;
  const volatile unsigned* p = (const volatile unsigned*)(f + (size_t)((lane<n)?lane:0)*CSTR);
  while (1) {
    unsigned v = *p;
    if (__all(v >= tgt)) break;
    __builtin_amdgcn_s_sleep(1);
  }
  asm volatile("" ::: "memory");
}
DI bf16x8 vld8(const u16* p){
  i32x4 v = *(const volatile i32x4*)p;
  bf16x8 r; __builtin_memcpy(&r, &v, 16); return r;
}
DI int get_xcc(){
  int x; asm volatile("s_getreg_b32 %0, hwreg(HW_REG_XCC_ID)" : "=s"(x)); return x & 0xff;
}

// ---------------- init ----------------
__global__ void k_init(const float* __restrict__ h0, u16* hb0, u16* hb1, u16* hb2, u16* hlo,
                       unsigned* cnt, unsigned* xccb, unsigned* flgb,
                       u16* hl0, u16* ll0, u16* hl1, u16* hl2){
  int i = blockIdx.x*256 + threadIdx.x;
  const int nA = 3*B_*HP, nA2 = B_*HP, nB = 4*TD*B_*16, nC = 4*FSLOT, nD = 8*FSLOT;
  const int nE = 4*2*B_*HP;
  if (i < nA) {
    int l = i/(B_*HP); int rem = i - l*(B_*HP); int b = rem/HP; int k = rem - b*HP;
    u16 v = (k<H) ? f2b(h0[l*800 + k]) : (u16)0;
    (l==0?hb0:(l==1?hb1:hb2))[(size_t)b*HP + k] = v;
  } else if (i < nA+nA2) {
    int rem = i - nA; int b = rem/HP; int k = rem - b*HP;
    u16 v = 0;
    if (k < H) { float w = h0[k]; u16 hi = f2b(w); v = f2b(w - b2f(hi)); }
    hlo[(size_t)b*HP + k] = v;
  } else if (i < nA+nA2+nB) {
    int q = i - nA - nA2; int buf = q/(TD*B_*16); int r2 = q % (TD*B_*16);
    int t = r2/(B_*16) + 1; int r3 = r2 % (B_*16); int b = r3>>4; int kk = r3&15;
    u16* hb = (buf==0)?hb0:((buf==1)?hb1:((buf==2)?hb2:hlo));
    hb[((size_t)t*B_ + b)*HP + 400 + kk] = 0;
  } else if (i < nA+nA2+nB+nC) {
    int q = i - nA - nA2 - nB;
    cnt[(size_t)q*CSTR] = 0u;
  } else if (i < nA+nA2+nB+nC+nD) {
    int q = i - nA - nA2 - nB - nC;
    if (q < 3*FSLOT) xccb[(size_t)q*CSTR] = 0u;
    else             flgb[(size_t)(q-3*FSLOT)*CSTR] = 0u;
  } else if (i < nA+nA2+nB+nC+nD+nE) {
    int q = i - nA - nA2 - nB - nC - nD;
    int buf = q / (2*B_*HP); int rem = q % (2*B_*HP);
    int k = rem % HP;
    u16 v = 0;
    if (k < H) {
      if (buf == 0)      v = f2b(h0[k]);
      else if (buf == 1) { float w = h0[k]; u16 hi = f2b(w); v = f2b(w - b2f(hi)); }
      else if (buf == 2) v = f2b(h0[800 + k]);
      else               v = f2b(h0[1600 + k]);
    }
    (buf==0?hl0:(buf==1?ll0:(buf==2?hl1:hl2)))[rem] = v;
  }
}

// ---------------- pack Whh ----------------
__global__ void k_apack(const float* W0, const float* W1, const float* W2,
                        u16* apkHi, u16* apkLo){
  int i = blockIdx.x*256 + threadIdx.x;
  const int total = 3*NBL*4*KT_H*64;
  if (i >= total) return;
  int lane = i & 63; int r = i >> 6;
  int kt = r % KT_H; r /= KT_H;
  int mt = r % 4;    r /= 4;
  int j  = r % NBL;  int lv = r / NBL;
  const float* W = (lv==0)?W0:((lv==1)?W1:W2);
  int row = mt*400 + j*16 + (lane & 15);
  int kbase = kt*32 + (lane>>4)*8;
  #pragma unroll
  for (int e=0;e<8;++e){
    int k = kbase+e;
    float w = (k<H) ? W[(size_t)row*H + k] : 0.f;
    u16 hi = f2b(w);
    apkHi[(size_t)i*8 + e] = hi;
    if (lv == 0) apkLo[(size_t)i*8 + e] = f2b(w - b2f(hi));
  }
}

// ---------------- pack Wih1/2 ----------------
__global__ void k_wihpack2(const float* __restrict__ W, u16* __restrict__ dst){
  int i = blockIdx.x*256 + threadIdx.x;
  if (i >= NBL*4*17*64) return;
  int lane = i & 63; int r = i >> 6;
  int ktf = r % 17; r /= 17; int mt = r % 4; int j = r / 4;
  int row = mt*400 + j*16 + (lane & 15);
  int kbase = ktf*32 + (lane>>4)*8;
  #pragma unroll
  for (int e=0;e<8;++e){
    int k = kbase+e;
    int col;
    if (ktf < 13) col = (k < 400) ? (3 + k) : -1;
    else          col = 403 + (k - 416);
    dst[(size_t)i*8 + e] = (col >= 0) ? f2b(W[(size_t)row*531 + col]) : (u16)0;
  }
}

// ---------------- pack out_W + biases ----------------
__global__ void k_smallpack(const float* outW,
                            const float* bi0, const float* bh0, const float* bi1, const float* bh1,
                            const float* bi2, const float* bh2,
                            u16* ouw, float* biasP){
  int i = blockIdx.x*256 + threadIdx.x;
  const int n2 = NOP*KOP, n3 = 3*1600;
  if (i < n2) {
    int n = i/KOP, k = i - n*KOP;
    ouw[i] = (n<OUTN && k<1200) ? f2b(outW[(size_t)n*1200 + k]) : (u16)0;
  } else if (i < n2+n3) {
    int q = i-n2; int l = q/1600, row = q - l*1600;
    const float* bi = (l==0)?bi0:((l==1)?bi1:bi2);
    const float* bh = (l==0)?bh0:((l==1)?bh1:bh2);
    biasP[q] = bi[row] + bh[row];
  }
}

// ---------------- strokes transpose ----------------
__global__ void k_packs(const float* __restrict__ strokes, float* __restrict__ st){
  int i = blockIdx.x*256 + threadIdx.x;
  if (i >= TD*B_) return;
  int t = i / B_, b = i & 63;
  st[(size_t)i*4+0] = strokes[((size_t)b*TD + t)*3 + 0];
  st[(size_t)i*4+1] = strokes[((size_t)b*TD + t)*3 + 1];
  st[(size_t)i*4+2] = strokes[((size_t)b*TD + t)*3 + 2];
  st[(size_t)i*4+3] = 0.f;
}

// ---------------- LSTM stage ----------------
template<int L, bool LOC>
DI void stage_lstm(char* smem, int j,
    const u16* __restrict__ apkHi, const u16* __restrict__ exG,
    const float* __restrict__ strokesT,
    const float* __restrict__ wihRaw, int wihStride,
    const float* __restrict__ biasL, const float* __restrict__ h0g,
    u16* __restrict__ hb_self, const u16* __restrict__ hb_prev,
    u16* __restrict__ hlo_, const u16* __restrict__ wbf,
    unsigned* __restrict__ fSelf, const unsigned* __restrict__ fDep, int nDep,
    u16* __restrict__ hloc, u16* __restrict__ lloc, unsigned* __restrict__ flgS,
    u16* __restrict__ pin, u16* __restrict__ win, unsigned* __restrict__ sgF)
{
  float* dumpS = (float*)(smem + LDS_DUMP);
  float* cL    = (float*)(smem + LDS_CL);
  u16*   exS   = (u16*)  (smem + LDS_EX);
  float* w3S   = (float*)(smem + LDS_W3);
  float* biasS = (float*)(smem + LDS_BIAS);
  const int tid = threadIdx.x, wv = tid>>6, l = tid&63;
  const int col = l&15, kg = l>>4;

  bf16x8 ahi[4][4];
  #pragma unroll
  for (int mt=0;mt<4;++mt)
    #pragma unroll
    for (int i=0;i<4;++i){
      int kt = wv + i*4;
      if (kt < KT_H) ahi[mt][i] = *(const bf16x8*)(apkHi + (size_t)j*26624 + ((size_t)(mt*KT_H + kt)*64 + l)*8);
      else { bf16x8 z = {0,0,0,0,0,0,0,0}; ahi[mt][i] = z; }
    }
  {
    const int nv = (L==0) ? 3328 : 4352;
    const size_t stride = (L==0) ? 26624 : 34816;
    const i32x4* src = (const i32x4*)(exG + (size_t)j*stride);
    i32x4* dst = (i32x4*)exS;
    for (int i = tid; i < nv; i += 256) dst[i] = src[i];
  }
  if (tid < 192) {
    int local = tid/3, c = tid - (tid/3)*3;
    int row = (local>>4)*400 + j*16 + (local&15);
    w3S[tid] = wihRaw[(size_t)row*wihStride + c];
  }
  if (tid < 64) {
    int row = (tid>>4)*400 + j*16 + (tid&15);
    biasS[tid] = biasL[row];
  }
  for (int i = tid; i < 1024; i += 256) cL[i] = h0g[L*800 + 400 + j*16 + (i>>6)];
  __syncthreads();

  for (int t = 1; t <= TD; ++t) {
    // ---- waits ----
    if (wv == 0) {
      if constexpr (L > 0) waitflags2(fDep, nDep, (unsigned)t, nullptr, 0, 0u);
      if constexpr (LOC)   waitloc(flgS, NBL, (unsigned)(t-1));
      else                 waitflags2(fSelf, NBL, (unsigned)(t-1), nullptr, 0, 0u);
    }
    __syncthreads();

    // ---- cooperative input staging: LLC -> XCD-local L2 (dedupe 25x) ----
    if constexpr (LOC && L > 0) {
      int idx = j + tid*NBL;
      if (idx < 3328) {
        const i32x4* srcH = (const i32x4*)(hb_prev + (size_t)t*B_*HP);
        ((i32x4*)(pin + (size_t)(t&1)*B_*HP))[idx] = srcH[idx];
      }
      if (idx < 1024) {
        const i32x4* srcW = (const i32x4*)(wbf + (size_t)(t-1)*B_*ENC);
        ((i32x4*)(win + (size_t)(t&1)*B_*ENC))[idx] = srcW[idx];
      }
      __syncthreads();   // drain copy stores into L2
      if (tid == 0) *((volatile unsigned*)(sgF + (size_t)j*CSTR)) = (unsigned)t;
      waitloc(sgF, NBL, (unsigned)t);
    }

    // ---- burst-issue B-operand loads ----
    const u16* hbase; const u16* lbase = nullptr;
    if constexpr (LOC) {
      hbase = hloc + (size_t)((t-1)&1)*B_*HP + kg*8;
      if constexpr (L==0) lbase = lloc + (size_t)((t-1)&1)*B_*HP + kg*8;
    } else {
      hbase = hb_self + (size_t)(t-1)*B_*HP + kg*8;
      if constexpr (L==0) lbase = hlo_ + (size_t)(t-1)*B_*HP + kg*8;
    }
    bf16x8 bh[4][4], bl[4][4], pf[5][4];
    #pragma unroll
    for (int i=0;i<4;++i){
      int kt = wv + i*4;
      if (kt < KT_H) {
        #pragma unroll
        for (int nt=0;nt<4;++nt){
          if constexpr (LOC) bh[i][nt] = vld8(hbase + (size_t)(nt*16+col)*HP + kt*32);
          else               bh[i][nt] = *(const bf16x8*)(hbase + (size_t)(nt*16+col)*HP + kt*32);
          if constexpr (L==0) {
            if constexpr (LOC) bl[i][nt] = vld8(lbase + (size_t)(nt*16+col)*HP + kt*32);
            else               bl[i][nt] = *(const bf16x8*)(lbase + (size_t)(nt*16+col)*HP + kt*32);
          }
        }
      }
    }
    if constexpr (L > 0) {
      const u16* pbase; const u16* wbase;
      if constexpr (LOC) {
        pbase = pin + (size_t)(t&1)*B_*HP + kg*8;
        wbase = win + (size_t)(t&1)*B_*ENC + kg*8;
      } else {
        pbase = hb_prev + (size_t)t*B_*HP + kg*8;
        wbase = wbf + ((size_t)(t-1)*B_)*ENC + kg*8;
      }
      #pragma unroll
      for (int i=0;i<5;++i){
        int ktf = wv + i*4;
        if (ktf < 17) {
          #pragma unroll
          for (int nt=0;nt<4;++nt){
            if (ktf < 13) {
              if constexpr (LOC) pf[i][nt] = vld8(pbase + (size_t)(nt*16+col)*HP + ktf*32);
              else               pf[i][nt] = *(const bf16x8*)(pbase + (size_t)(nt*16+col)*HP + ktf*32);
            } else {
              if constexpr (LOC) pf[i][nt] = vld8(wbase + (size_t)(nt*16+col)*ENC + (ktf-13)*32);
              else               pf[i][nt] = *(const bf16x8*)(wbase + (size_t)(nt*16+col)*ENC + (ktf-13)*32);
            }
          }
        }
      }
    }

    // ---- MFMAs ----
    f32x4 acc[4][4];
    #pragma unroll
    for (int mt=0;mt<4;++mt)
      #pragma unroll
      for (int nt=0;nt<4;++nt){ f32x4 z = {0.f,0.f,0.f,0.f}; acc[mt][nt] = z; }
    #pragma unroll
    for (int i=0;i<4;++i){
      int kt = wv + i*4;
      if (kt < KT_H) {
        #pragma unroll
        for (int mt=0;mt<4;++mt){
          bf16x8 a = ahi[mt][i];
          #pragma unroll
          for (int nt=0;nt<4;++nt)
            acc[mt][nt] = __builtin_amdgcn_mfma_f32_16x16x32_bf16(a, bh[i][nt], acc[mt][nt], 0,0,0);
          if constexpr (L==0) {
            bf16x8 al = *(const bf16x8*)(exS + ((size_t)(mt*KT_H + kt)*64 + l)*8);
            #pragma unroll
            for (int nt=0;nt<4;++nt){
              acc[mt][nt] = __builtin_amdgcn_mfma_f32_16x16x32_bf16(a,  bl[i][nt], acc[mt][nt], 0,0,0);
              acc[mt][nt] = __builtin_amdgcn_mfma_f32_16x16x32_bf16(al, bh[i][nt], acc[mt][nt], 0,0,0);
            }
          }
        }
      }
    }
    if constexpr (L > 0) {
      #pragma unroll
      for (int i=0;i<5;++i){
        int ktf = wv + i*4;
        if (ktf < 17) {
          #pragma unroll
          for (int mt=0;mt<4;++mt){
            bf16x8 a = *(const bf16x8*)(exS + ((size_t)(mt*17 + ktf)*64 + l)*8);
            #pragma unroll
            for (int nt=0;nt<4;++nt)
              acc[mt][nt] = __builtin_amdgcn_mfma_f32_16x16x32_bf16(a, pf[i][nt], acc[mt][nt], 0,0,0);
          }
        }
      }
    }
    // dump partials
    #pragma unroll
    for (int mt=0;mt<4;++mt)
      #pragma unroll
      for (int nt=0;nt<4;++nt)
        #pragma unroll
        for (int r=0;r<4;++r)
          dumpS[wv*4160 + (mt*16 + kg*4 + r)*65 + nt*16 + col] = acc[mt][nt][r];
    __syncthreads();
    // gates
    {
      const int bg = tid & 63, uq = tid >> 6;
      const float* sp = strokesT + ((size_t)(t-1)*B_ + bg)*4;
      float sx = sp[0], sy = sp[1], sz = sp[2];
      u16x4 hh4, ll4;
      #pragma unroll
      for (int e=0;e<4;++e){
        int u = uq*4 + e;
        int idx = u*64 + bg;
        float gv[4];
        #pragma unroll
        for (int g=0; g<4; ++g){
          int row = g*16 + u;
          float s = dumpS[row*65 + bg] + dumpS[4160 + row*65 + bg]
                  + dumpS[8320 + row*65 + bg] + dumpS[12480 + row*65 + bg];
          s += biasS[row] + w3S[row*3+0]*sx + w3S[row*3+1]*sy + w3S[row*3+2]*sz;
          gv[g] = s;
        }
        float co = cL[idx];
        float i_ = sigm(gv[0]), f_ = sigm(gv[1]), g_ = tanh_(gv[2]), o_ = sigm(gv[3]);
        float cn = f_*co + i_*g_;
        cL[idx] = cn;
        float hv = o_*tanh_(cn);
        u16 hh = f2b(hv);
        hh4[e] = hh;
        if constexpr (L==0) ll4[e] = f2b(hv - b2f(hh));
      }
      if constexpr (LOC) {
        *(u16x4*)(hloc + ((size_t)(t&1)*B_ + bg)*HP + j*16 + uq*4) = hh4;
        if constexpr (L==0) *(u16x4*)(lloc + ((size_t)(t&1)*B_ + bg)*HP + j*16 + uq*4) = ll4;
        if constexpr (L==2) {
          *(u16x4*)(hb_self + ((size_t)t*B_ + bg)*HP + j*16 + uq*4) = hh4;
        } else {
          st8(hb_self + ((size_t)t*B_ + bg)*HP + j*16 + uq*4, hh4);
          if constexpr (L==0) st8(hlo_ + ((size_t)t*B_ + bg)*HP + j*16 + uq*4, ll4);
        }
      } else {
        st8(hb_self + ((size_t)t*B_ + bg)*HP + j*16 + uq*4, hh4);
        if constexpr (L==0) st8(hlo_ + ((size_t)t*B_ + bg)*HP + j*16 + uq*4, ll4);
      }
    }
    __syncthreads();   // drains stores before flags
    if (tid == 0) {
      if constexpr (LOC) *((volatile unsigned*)(flgS + (size_t)j*CSTR)) = (unsigned)t;
      setflag(fSelf + (size_t)j*CSTR, (unsigned)t);
    }
  }
}

// ---------------- attention stage ----------------
DI void stage_attn(char* smem, int j2,
    const float* __restrict__ ctx, const float* __restrict__ cmask,
    const float* __restrict__ attnW, const float* __restrict__ attnB,
    const u16* __restrict__ hb0, const u16* __restrict__ hlo_,
    u16* __restrict__ wbf,
    const unsigned* __restrict__ fA, unsigned* __restrict__ fB)
{
  float* ctxS = (float*)(smem + ALDS_CTX);
  float* atwS = (float*)(smem + ALDS_ATW);
  float* hS   = (float*)(smem + ALDS_H);
  float* phiS = (float*)(smem + ALDS_PHI);
  float* mskS = (float*)(smem + ALDS_MSK);
  float* kapS = (float*)(smem + ALDS_KAP);
  float* pS   = (float*)(smem + ALDS_P);
  float* ppsS = (float*)(smem + ALDS_PPS);
  const int tid = threadIdx.x;
  const int b0 = j2*2;
  for (int i = tid; i < 2*80*128; i += 256) {
    int bi = i/10240, rem = i%10240;
    ctxS[i] = ctx[(size_t)(b0+bi)*10240 + rem];
  }
  for (int i = tid; i < 30*400; i += 256) {
    int row = i/400, k = i - row*400;
    atwS[row*401 + k] = attnW[i];
  }
  for (int i = tid; i < 160; i += 256) {
    int bi = i/80, u = i - bi*80;
    mskS[i] = cmask[(b0+bi)*80 + u];
  }
  if (tid < 20) kapS[tid] = 0.f;
  float aB = (tid < 60) ? attnB[tid % 30] : 0.f;
  __syncthreads();

  for (int t = 1; t <= TD; ++t) {
    if ((tid>>6) == 0) waitflags2(fA, NBL, (unsigned)t, nullptr, 0, 0u);
    __syncthreads();
    if (tid < 200) {
      int bi = tid/100, k = (tid%100)*4;
      size_t off = ((size_t)t*B_ + (b0+bi))*HP + k;
      u16x4 hi4 = *(const u16x4*)(hb0 + off);
      u16x4 lo4 = *(const u16x4*)(hlo_ + off);
      #pragma unroll
      for (int e=0;e<4;++e) hS[bi*400 + k + e] = b2f(hi4[e]) + b2f(lo4[e]);
    }
    __syncthreads();
    if (tid < 240) {
      int bi = tid/120, r = tid - bi*120;
      int row = r>>2, seg = r&3;
      const float* ar = atwS + row*401 + seg*100;
      const float* hr = hS + bi*400 + seg*100;
      float a0=0,a1=0,a2=0,a3=0;
      #pragma unroll 4
      for (int k=0;k<100;k+=4){
        a0 += ar[k]*hr[k]; a1 += ar[k+1]*hr[k+1];
        a2 += ar[k+2]*hr[k+2]; a3 += ar[k+3]*hr[k+3];
      }
      ppsS[(bi*30+row)*4+seg] = a0+a1+a2+a3;
    }
    __syncthreads();
    if (tid < 60) {
      int bi = tid/30, row = tid - bi*30;
      const float* pp = ppsS + (bi*30+row)*4;
      pS[bi*30+row] = __expf(pp[0]+pp[1]+pp[2]+pp[3] + aB);
    }
    __syncthreads();
    if (tid < 20) {
      int bi = tid/10, m = tid - bi*10;
      kapS[tid] += 0.2f * pS[bi*30 + 20 + m];
    }
    __syncthreads();
    if (tid < 160) {
      int bi = tid/80; float u2 = (float)(tid - bi*80);
      const float* pb = pS + bi*30; const float* kb = kapS + bi*10;
      float a = 0.f;
      #pragma unroll
      for (int m=0;m<10;++m){ float d = kb[m]-u2; a += pb[m]*__expf(-pb[10+m]*d*d); }
      phiS[tid] = a * mskS[tid];
    }
    __syncthreads();
    {
      int bi = tid >> 7, e = tid & 127;
      const float* ph = phiS + bi*80;
      const float* cs = ctxS + (size_t)bi*10240 + e;
      float a = 0.f;
      for (int u = 0; u < TC; ++u) a += ph[u]*cs[u*128];
      st16(wbf + ((size_t)(t-1)*B_ + (b0+bi))*ENC + e, f2b(a));
    }
    __syncthreads();
    if (tid == 0) setflag(fB + (size_t)j2*CSTR, (unsigned)t);
  }
}

// ---------------- xcc uniformity check ----------------
DI bool xcc_check(char* smem, int stage, int j, unsigned* xccb){
  unsigned* xs = xccb + (size_t)stage*FSLOT*CSTR;
  if (threadIdx.x == 0) setflag(xs + (size_t)j*CSTR, 0x100u | (unsigned)get_xcc());
  if ((threadIdx.x>>6) == 0) {
    waitflags2(xs, NBL, 0x100u, nullptr, 0, 0u);
    int lane = threadIdx.x & 63;
    unsigned v = __hip_atomic_load(xs + (size_t)((lane<NBL)?lane:0)*CSTR,
                                   __ATOMIC_RELAXED, __HIP_MEMORY_SCOPE_AGENT);
    unsigned r0 = __shfl(v, 0);
    int uni = __all(v == r0) ? 1 : 0;
    if (threadIdx.x == 0) *(int*)(smem + LDS_VERD) = uni;
  }
  __syncthreads();
  return (*(int*)(smem + LDS_VERD)) != 0;
}

// ---------------- mega kernel ----------------
__global__ __launch_bounds__(256,1) void k_mega(
    const u16* apkH, const u16* apkL, const u16* wf1, const u16* wf2,
    const float* strokesT, const float* Wih0, const float* Wih1, const float* Wih2,
    const float* bia, const float* h0g,
    u16* hb0, u16* hb1, u16* hb2, u16* hlo, u16* wbf,
    const float* ctx, const float* cmask, const float* attnW, const float* attnB,
    unsigned* cnt, unsigned* xccb, unsigned* flgb,
    u16* hl0, u16* ll0, u16* hl1, u16* hl2,
    u16* pi1, u16* wi1, u16* pi2, u16* wi2)
{
  extern __shared__ char smem[];
  unsigned* fA = cnt;
  unsigned* fB = cnt + (size_t)FSLOT*CSTR;
  unsigned* fC = cnt + (size_t)2*FSLOT*CSTR;
  unsigned* fD = cnt + (size_t)3*FSLOT*CSTR;
  int b = blockIdx.x; int colx = b & 7; int row = b >> 3;
  if (colx == 0 && row < NBL) {
    bool loc = xcc_check(smem, 0, row, xccb);
    if (loc) stage_lstm<0,true >(smem, row, apkH, apkL, strokesT, Wih0, 3, bia, h0g,
                  hb0, nullptr, hlo, nullptr, fA, nullptr, 0, hl0, ll0, flgb,
                  nullptr, nullptr, nullptr);
    else     stage_lstm<0,false>(smem, row, apkH, apkL, strokesT, Wih0, 3, bia, h0g,
                  hb0, nullptr, hlo, nullptr, fA, nullptr, 0, hl0, ll0, flgb,
                  nullptr, nullptr, nullptr);
  } else if ((colx == 1 || colx == 2) && row < 16) {
    int j2 = (colx-1)*16 + row;
    stage_attn(smem, j2, ctx, cmask, attnW, attnB, hb0, hlo, wbf, fA, fB);
  } else if (colx == 3 && row < NBL) {
    bool loc = xcc_check(smem, 1, row, xccb);
    unsigned* fg = flgb + (size_t)FSLOT*CSTR;
    unsigned* sg = flgb + (size_t)3*FSLOT*CSTR;
    if (loc) stage_lstm<1,true >(smem, row, apkH + (size_t)1*NBL*26624, wf1, strokesT, Wih1, 531,
                  bia+1600, h0g, hb1, hb0, nullptr, wbf, fC, fB, NBA, hl1, nullptr, fg,
                  pi1, wi1, sg);
    else     stage_lstm<1,false>(smem, row, apkH + (size_t)1*NBL*26624, wf1, strokesT, Wih1, 531,
                  bia+1600, h0g, hb1, hb0, nullptr, wbf, fC, fB, NBA, hl1, nullptr, fg,
                  pi1, wi1, sg);
  } else if (colx == 4 && row < NBL) {
    bool loc = xcc_check(smem, 2, row, xccb);
    unsigned* fg = flgb + (size_t)2*FSLOT*CSTR;
    unsigned* sg = flgb + (size_t)4*FSLOT*CSTR;
    if (loc) stage_lstm<2,true >(smem, row, apkH + (size_t)2*NBL*26624, wf2, strokesT, Wih2, 531,
                  bia+3200, h0g, hb2, hb1, nullptr, wbf, fD, fC, NBL, hl2, nullptr, fg,
                  pi2, wi2, sg);
    else     stage_lstm<2,false>(smem, row, apkH + (size_t)2*NBL*26624, wf2, strokesT, Wih2, 531,
                  bia+3200, h0g, hb2, hb1, nullptr, wbf, fD, fC, NBL, hl2, nullptr, fg,
                  pi2, wi2, sg);
  }
}

// ---------------- output projection -> f32 d_out ----------------
__global__ __launch_bounds__(256) void k_gemm_out(const u16* __restrict__ hb0, const u16* __restrict__ hb1,
                                                  const u16* __restrict__ hb2, const u16* __restrict__ ouw,
                                                  const float* __restrict__ out_b, float* __restrict__ dout){
  int wv = threadIdx.x>>6, l = threadIdx.x&63;
  int task = blockIdx.x*4 + wv;
  int ng = task & 1; int mpair = task >> 1;
  int m0 = mpair*32; int t = m0>>6; int broff = m0 & 63;
  int col = l&15, kg = l>>4;
  f32x4 acc[2][4];
  #pragma unroll
  for (int mt=0;mt<2;++mt)
    #pragma unroll
    for (int nt=0;nt<4;++nt){ f32x4 z = {0.f,0.f,0.f,0.f}; acc[mt][nt] = z; }
  for (int kt=0; kt<38; ++kt) {
    int k0 = kt*32 + kg*8;
    int reg = (k0>=800) ? 2 : ((k0>=400) ? 1 : 0);
    int koff = k0 - reg*400;
    const u16* hb = (reg==0) ? hb0 : ((reg==1) ? hb1 : hb2);
    bf16x8 afr[2];
    #pragma unroll
    for (int mt=0;mt<2;++mt)
      afr[mt] = *(const bf16x8*)(hb + ((size_t)(t+1)*B_ + broff + mt*16 + col)*HP + koff);
    #pragma unroll
    for (int nt=0;nt<4;++nt) {
      bf16x8 bfr = *(const bf16x8*)(ouw + (size_t)(ng*64 + nt*16 + col)*KOP + k0);
      #pragma unroll
      for (int mt=0;mt<2;++mt)
        acc[mt][nt] = __builtin_amdgcn_mfma_f32_16x16x32_bf16(afr[mt], bfr, acc[mt][nt], 0,0,0);
    }
  }
  #pragma unroll
  for (int mt=0;mt<2;++mt)
    #pragma unroll
    for (int nt=0;nt<4;++nt)
      #pragma unroll
      for (int r=0;r<4;++r) {
        int n = ng*64 + nt*16 + col;
        int bo = broff + mt*16 + kg*4 + r;
        if (n < OUTN) dout[((size_t)bo*TD + t)*OUTN + n] = acc[mt][nt][r] + out_b[n];
      }
}

__global__ void k_sentinel(float* o, float code){ o[threadIdx.x] = code; }

// ---------------- host ----------------
extern "C" void kernel_launch(void* const* d_in, const int* in_sizes, int n_in,
                              void* d_out, int out_size, void* d_ws, size_t ws_size,
                              hipStream_t stream) {
  const float* strokes = (const float*)d_in[0];
  const float* context = (const float*)d_in[1];
  const float* cmask   = (const float*)d_in[2];
  const float* h0      = (const float*)d_in[3];
  const float* Wih0 = (const float*)d_in[4];  const float* Whh0 = (const float*)d_in[5];
  const float* bih0 = (const float*)d_in[6];  const float* bhh0 = (const float*)d_in[7];
  const float* Wih1 = (const float*)d_in[8];  const float* Whh1 = (const float*)d_in[9];
  const float* bih1 = (const float*)d_in[10]; const float* bhh1 = (const float*)d_in[11];
  const float* Wih2 = (const float*)d_in[12]; const float* Whh2 = (const float*)d_in[13];
  const float* bih2 = (const float*)d_in[14]; const float* bhh2 = (const float*)d_in[15];
  const float* attnW = (const float*)d_in[16]; const float* attnB = (const float*)d_in[17];
  const float* outW  = (const float*)d_in[18]; const float* outB  = (const float*)d_in[19];
  float* dout = (float*)d_out;

  if (ws_size < WS_NEED) {
    float code = 1000.0f + (float)(ws_size >> 20);
    k_sentinel<<<1, 64, 0, stream>>>(dout, code);
    return;
  }

  char* ws = (char*)d_ws;
  u16* hb0 = (u16*)(ws + OFF_HB0);
  u16* hb1 = (u16*)(ws + OFF_HB1);
  u16* hb2 = (u16*)(ws + OFF_HB2);
  u16* hlo = (u16*)(ws + OFF_HLO);
  u16* wbf = (u16*)(ws + OFF_WBF);
  float* strT = (float*)(ws + OFF_STR);
  u16* apkH = (u16*)(ws + OFF_APKH);
  u16* apkL = (u16*)(ws + OFF_APKL);
  u16* wf1  = (u16*)(ws + OFF_WF1);
  u16* wf2  = (u16*)(ws + OFF_WF2);
  u16* ouw  = (u16*)(ws + OFF_OUW);
  float* bia = (float*)(ws + OFF_BIA);
  unsigned* cnt = (unsigned*)(ws + OFF_CNT);
  unsigned* xccb = (unsigned*)(ws + OFF_XCC);
  unsigned* flgb = (unsigned*)(ws + OFF_FLG);
  u16* hl0 = (u16*)(ws + OFF_HL0);
  u16* ll0 = (u16*)(ws + OFF_LL0);
  u16* hl1 = (u16*)(ws + OFF_HL1);
  u16* hl2 = (u16*)(ws + OFF_HL2);
  u16* pi1 = (u16*)(ws + OFF_PI1);
  u16* wi1 = (u16*)(ws + OFF_WI1);
  u16* pi2 = (u16*)(ws + OFF_PI2);
  u16* wi2 = (u16*)(ws + OFF_WI2);

  (void)hipFuncSetAttribute((const void*)k_mega, hipFuncAttributeMaxDynamicSharedMemorySize, LDSB);

  {
    int n = 3*B_*HP + B_*HP + 4*TD*B_*16 + 4*FSLOT + 8*FSLOT + 4*2*B_*HP;
    k_init<<<(n+255)/256, 256, 0, stream>>>(h0, hb0, hb1, hb2, hlo, cnt, xccb, flgb, hl0, ll0, hl1, hl2);
  }
  k_apack<<<(3*NBL*4*KT_H*64+255)/256, 256, 0, stream>>>(Whh0, Whh1, Whh2, apkH, apkL);
  k_wihpack2<<<(NBL*4*17*64+255)/256, 256, 0, stream>>>(Wih1, wf1);
  k_wihpack2<<<(NBL*4*17*64+255)/256, 256, 0, stream>>>(Wih2, wf2);
  {
    int n = NOP*KOP + 3*1600;
    k_smallpack<<<(n+255)/256, 256, 0, stream>>>(outW, bih0,bhh0,bih1,bhh1,bih2,bhh2, ouw, bia);
  }
  k_packs<<<(TD*B_+255)/256, 256, 0, stream>>>(strokes, strT);

  // ---- fused pipelined recurrence (256-block grid, XCD-column layout) ----
  k_mega<<<256, 256, LDSB, stream>>>(apkH, apkL, wf1, wf2,
      strT, Wih0, Wih1, Wih2, bia, h0,
      hb0, hb1, hb2, hlo, wbf,
      context, cmask, attnW, attnB, cnt, xccb, flgb, hl0, ll0, hl1, hl2,
      pi1, wi1, pi2, wi2);

  // ---- output projection ----
  k_gemm_out<<<3200/4, 256, 0, stream>>>(hb0, hb1, hb2, ouw, outB, dout);
}

// Round 16
// 8544.567 us; speedup vs baseline: 1.0215x; 1.0215x over previous
//
#include <hip/hip_runtime.h>
#include <stdint.h>

typedef unsigned short u16;
typedef __attribute__((ext_vector_type(8))) short bf16x8;
typedef __attribute__((ext_vector_type(4))) float f32x4;
typedef __attribute__((ext_vector_type(4))) int   i32x4;
typedef __attribute__((ext_vector_type(4))) unsigned short u16x4;

#define DI static __device__ __forceinline__

constexpr int B_   = 64;
constexpr int TD   = 800;
constexpr int TC   = 80;
constexpr int ENC  = 128;
constexpr int H    = 400;
constexpr int OUTN = 121;

constexpr int HP   = 416;
constexpr int KT_H = 13;
constexpr int KOP  = 1216;
constexpr int NOP  = 128;
constexpr int NBL  = 25;
constexpr int NBA  = 32;
constexpr int CSTR = 32;
constexpr int FSLOT= 32;

// ---------------- workspace layout ----------------
constexpr size_t HB_B  = (size_t)(TD+1)*B_*HP*2;
constexpr size_t WBF_B = (size_t)TD*B_*ENC*2;
constexpr size_t STR_B = (size_t)TD*B_*4*4;
constexpr size_t APK_B = (size_t)NBL*4*KT_H*64*8*2;
constexpr size_t WF_B  = (size_t)NBL*4*17*64*8*2;
constexpr size_t LOC_B = (size_t)2*B_*HP*2;
constexpr size_t PIN_B = (size_t)2*B_*HP*2;     // staged h_prev (double buf)
constexpr size_t WIN_B = (size_t)2*B_*ENC*2;    // staged w (double buf)

constexpr size_t OFF_HB0 = 0;
constexpr size_t OFF_HB1 = OFF_HB0 + HB_B;
constexpr size_t OFF_HB2 = OFF_HB1 + HB_B;
constexpr size_t OFF_HLO = OFF_HB2 + HB_B;
constexpr size_t OFF_WBF = OFF_HLO + HB_B;
constexpr size_t OFF_STR = OFF_WBF + WBF_B;
constexpr size_t OFF_APKH= OFF_STR + STR_B;
constexpr size_t OFF_APKL= OFF_APKH + 3*APK_B;
constexpr size_t OFF_WF1 = OFF_APKL + APK_B;
constexpr size_t OFF_WF2 = OFF_WF1 + WF_B;
constexpr size_t OFF_OUW = OFF_WF2 + WF_B;
constexpr size_t OFF_BIA = OFF_OUW + (size_t)NOP*KOP*2;
constexpr size_t OFF_CNT = OFF_BIA + (size_t)3*1600*4;
constexpr size_t OFF_XCC = OFF_CNT + (size_t)4*FSLOT*CSTR*4;
constexpr size_t OFF_FLG = OFF_XCC + (size_t)3*FSLOT*CSTR*4;   // 5 slots: 3 self + 2 stage
constexpr size_t OFF_HL0 = OFF_FLG + (size_t)5*FSLOT*CSTR*4;
constexpr size_t OFF_LL0 = OFF_HL0 + LOC_B;
constexpr size_t OFF_HL1 = OFF_LL0 + LOC_B;
constexpr size_t OFF_HL2 = OFF_HL1 + LOC_B;
constexpr size_t OFF_PI1 = OFF_HL2 + LOC_B;
constexpr size_t OFF_WI1 = OFF_PI1 + PIN_B;
constexpr size_t OFF_PI2 = OFF_WI1 + WIN_B;
constexpr size_t OFF_WI2 = OFF_PI2 + PIN_B;
constexpr size_t WS_NEED = OFF_WI2 + WIN_B + 256;

// LDS offsets
constexpr int LDS_DUMP = 0;
constexpr int LDS_CL   = 66560;
constexpr int LDS_EX   = 70656;
constexpr int LDS_W3   = 140288;
constexpr int LDS_BIAS = 141056;
constexpr int LDS_VERD = 141312;
constexpr int LDSB     = 141568;
constexpr int ALDS_CTX = 0;
constexpr int ALDS_ATW = 81920;
constexpr int ALDS_H   = 130040;
constexpr int ALDS_PHI = 133240;
constexpr int ALDS_MSK = 133880;
constexpr int ALDS_KAP = 134520;
constexpr int ALDS_P   = 134600;
constexpr int ALDS_PPS = 134840;

DI u16 f2b(float f){ union{float f; unsigned u;} v; v.f=f; unsigned r = v.u + 0x7FFFu + ((v.u>>16)&1u); return (u16)(r>>16); }
DI float b2f(u16 h){ union{unsigned u; float f;} v; v.u=((unsigned)h)<<16; return v.f; }
DI float sigm(float x){ return 1.f/(1.f+__expf(-x)); }
DI float tanh_(float x){ float a=fabsf(x), e=__expf(-2.f*a), t=(1.f-e)/(1.f+e); return x<0.f ? -t : t; }

DI void st16(u16* p, u16 v){
  asm volatile("global_store_short %0, %1, off sc0 sc1" :: "v"(p), "v"((unsigned)v) : "memory");
}
DI void st8(u16* p, u16x4 v){
  unsigned long long x; __builtin_memcpy(&x, &v, 8);
  asm volatile("global_store_dwordx2 %0, %1, off sc0 sc1" :: "v"(p), "v"(x) : "memory");
}
DI void setflag(unsigned* p, unsigned t){
  asm volatile("global_store_dword %0, %1, off sc0 sc1" :: "v"(p), "v"(t) : "memory");
}
// LLC flag wait (relaxed gather)
DI void waitflags2(const unsigned* fA, int nA, unsigned tA,
                   const unsigned* fB, int nB, unsigned tB){
  int lane = threadIdx.x & 63;
  const unsigned* p; unsigned tgt;
  if (lane < nA)            { p = fA + (size_t)lane*CSTR;        tgt = tA; }
  else if (lane < nA+nB)    { p = fB + (size_t)(lane-nA)*CSTR;   tgt = tB; }
  else                      { p = fA;                            tgt = 0;  }
  while (1) {
    unsigned v = __hip_atomic_load(p, __ATOMIC_RELAXED, __HIP_MEMORY_SCOPE_AGENT);
    if (__all(v >= tgt)) break;
    __builtin_amdgcn_s_sleep(1);
  }
  asm volatile("" ::: "memory");
}
// XCD-local flag wait: volatile poll with light sleep
DI void waitloc(const unsigned* f, int n, unsigned tgt){
  int lane = threadIdx.x & 63;
  const volatile unsigned* p = (const volatile unsigned*)(f + (size_t)((lane<n)?lane:0)*CSTR);
  while (1) {
    unsigned v = *p;
    if (__all(v >= tgt)) break;
    __builtin_amdgcn_s_sleep(1);
  }
  asm volatile("" ::: "memory");
}
DI bf16x8 vld8(const u16* p){
  i32x4 v = *(const volatile i32x4*)p;
  bf16x8 r; __builtin_memcpy(&r, &v, 16); return r;
}
DI int get_xcc(){
  int x; asm volatile("s_getreg_b32 %0, hwreg(HW_REG_XCC_ID)" : "=s"(x)); return x & 0xff;
}

// ---------------- init ----------------
__global__ void k_init(const float* __restrict__ h0, u16* hb0, u16* hb1, u16* hb2, u16* hlo,
                       unsigned* cnt, unsigned* xccb, unsigned* flgb,
                       u16* hl0, u16* ll0, u16* hl1, u16* hl2){
  int i = blockIdx.x*256 + threadIdx.x;
  const int nA = 3*B_*HP, nA2 = B_*HP, nB = 4*TD*B_*16, nC = 4*FSLOT, nD = 8*FSLOT;
  const int nE = 4*2*B_*HP;
  if (i < nA) {
    int l = i/(B_*HP); int rem = i - l*(B_*HP); int b = rem/HP; int k = rem - b*HP;
    u16 v = (k<H) ? f2b(h0[l*800 + k]) : (u16)0;
    (l==0?hb0:(l==1?hb1:hb2))[(size_t)b*HP + k] = v;
  } else if (i < nA+nA2) {
    int rem = i - nA; int b = rem/HP; int k = rem - b*HP;
    u16 v = 0;
    if (k < H) { float w = h0[k]; u16 hi = f2b(w); v = f2b(w - b2f(hi)); }
    hlo[(size_t)b*HP + k] = v;
  } else if (i < nA+nA2+nB) {
    int q = i - nA - nA2; int buf = q/(TD*B_*16); int r2 = q % (TD*B_*16);
    int t = r2/(B_*16) + 1; int r3 = r2 % (B_*16); int b = r3>>4; int kk = r3&15;
    u16* hb = (buf==0)?hb0:((buf==1)?hb1:((buf==2)?hb2:hlo));
    hb[((size_t)t*B_ + b)*HP + 400 + kk] = 0;
  } else if (i < nA+nA2+nB+nC) {
    int q = i - nA - nA2 - nB;
    cnt[(size_t)q*CSTR] = 0u;
  } else if (i < nA+nA2+nB+nC+nD) {
    int q = i - nA - nA2 - nB - nC;
    if (q < 3*FSLOT) xccb[(size_t)q*CSTR] = 0u;
    else             flgb[(size_t)(q-3*FSLOT)*CSTR] = 0u;
  } else if (i < nA+nA2+nB+nC+nD+nE) {
    int q = i - nA - nA2 - nB - nC - nD;
    int buf = q / (2*B_*HP); int rem = q % (2*B_*HP);
    int k = rem % HP;
    u16 v = 0;
    if (k < H) {
      if (buf == 0)      v = f2b(h0[k]);
      else if (buf == 1) { float w = h0[k]; u16 hi = f2b(w); v = f2b(w - b2f(hi)); }
      else if (buf == 2) v = f2b(h0[800 + k]);
      else               v = f2b(h0[1600 + k]);
    }
    (buf==0?hl0:(buf==1?ll0:(buf==2?hl1:hl2)))[rem] = v;
  }
}

// ---------------- pack Whh ----------------
__global__ void k_apack(const float* W0, const float* W1, const float* W2,
                        u16* apkHi, u16* apkLo){
  int i = blockIdx.x*256 + threadIdx.x;
  const int total = 3*NBL*4*KT_H*64;
  if (i >= total) return;
  int lane = i & 63; int r = i >> 6;
  int kt = r % KT_H; r /= KT_H;
  int mt = r % 4;    r /= 4;
  int j  = r % NBL;  int lv = r / NBL;
  const float* W = (lv==0)?W0:((lv==1)?W1:W2);
  int row = mt*400 + j*16 + (lane & 15);
  int kbase = kt*32 + (lane>>4)*8;
  #pragma unroll
  for (int e=0;e<8;++e){
    int k = kbase+e;
    float w = (k<H) ? W[(size_t)row*H + k] : 0.f;
    u16 hi = f2b(w);
    apkHi[(size_t)i*8 + e] = hi;
    if (lv == 0) apkLo[(size_t)i*8 + e] = f2b(w - b2f(hi));
  }
}

// ---------------- pack Wih1/2 ----------------
__global__ void k_wihpack2(const float* __restrict__ W, u16* __restrict__ dst){
  int i = blockIdx.x*256 + threadIdx.x;
  if (i >= NBL*4*17*64) return;
  int lane = i & 63; int r = i >> 6;
  int ktf = r % 17; r /= 17; int mt = r % 4; int j = r / 4;
  int row = mt*400 + j*16 + (lane & 15);
  int kbase = ktf*32 + (lane>>4)*8;
  #pragma unroll
  for (int e=0;e<8;++e){
    int k = kbase+e;
    int col;
    if (ktf < 13) col = (k < 400) ? (3 + k) : -1;
    else          col = 403 + (k - 416);
    dst[(size_t)i*8 + e] = (col >= 0) ? f2b(W[(size_t)row*531 + col]) : (u16)0;
  }
}

// ---------------- pack out_W + biases ----------------
__global__ void k_smallpack(const float* outW,
                            const float* bi0, const float* bh0, const float* bi1, const float* bh1,
                            const float* bi2, const float* bh2,
                            u16* ouw, float* biasP){
  int i = blockIdx.x*256 + threadIdx.x;
  const int n2 = NOP*KOP, n3 = 3*1600;
  if (i < n2) {
    int n = i/KOP, k = i - n*KOP;
    ouw[i] = (n<OUTN && k<1200) ? f2b(outW[(size_t)n*1200 + k]) : (u16)0;
  } else if (i < n2+n3) {
    int q = i-n2; int l = q/1600, row = q - l*1600;
    const float* bi = (l==0)?bi0:((l==1)?bi1:bi2);
    const float* bh = (l==0)?bh0:((l==1)?bh1:bh2);
    biasP[q] = bi[row] + bh[row];
  }
}

// ---------------- strokes transpose ----------------
__global__ void k_packs(const float* __restrict__ strokes, float* __restrict__ st){
  int i = blockIdx.x*256 + threadIdx.x;
  if (i >= TD*B_) return;
  int t = i / B_, b = i & 63;
  st[(size_t)i*4+0] = strokes[((size_t)b*TD + t)*3 + 0];
  st[(size_t)i*4+1] = strokes[((size_t)b*TD + t)*3 + 1];
  st[(size_t)i*4+2] = strokes[((size_t)b*TD + t)*3 + 2];
  st[(size_t)i*4+3] = 0.f;
}

// ---------------- LSTM stage ----------------
template<int L, bool LOC>
DI void stage_lstm(char* smem, int j,
    const u16* __restrict__ apkHi, const u16* __restrict__ exG,
    const float* __restrict__ strokesT,
    const float* __restrict__ wihRaw, int wihStride,
    const float* __restrict__ biasL, const float* __restrict__ h0g,
    u16* __restrict__ hb_self, const u16* __restrict__ hb_prev,
    u16* __restrict__ hlo_, const u16* __restrict__ wbf,
    unsigned* __restrict__ fSelf, const unsigned* __restrict__ fDep, int nDep,
    u16* __restrict__ hloc, u16* __restrict__ lloc, unsigned* __restrict__ flgS,
    u16* __restrict__ pin, u16* __restrict__ win, unsigned* __restrict__ sgF)
{
  float* dumpS = (float*)(smem + LDS_DUMP);
  float* cL    = (float*)(smem + LDS_CL);
  u16*   exS   = (u16*)  (smem + LDS_EX);
  float* w3S   = (float*)(smem + LDS_W3);
  float* biasS = (float*)(smem + LDS_BIAS);
  const int tid = threadIdx.x, wv = tid>>6, l = tid&63;
  const int col = l&15, kg = l>>4;

  bf16x8 ahi[4][4];
  #pragma unroll
  for (int mt=0;mt<4;++mt)
    #pragma unroll
    for (int i=0;i<4;++i){
      int kt = wv + i*4;
      if (kt < KT_H) ahi[mt][i] = *(const bf16x8*)(apkHi + (size_t)j*26624 + ((size_t)(mt*KT_H + kt)*64 + l)*8);
      else { bf16x8 z = {0,0,0,0,0,0,0,0}; ahi[mt][i] = z; }
    }
  {
    const int nv = (L==0) ? 3328 : 4352;
    const size_t stride = (L==0) ? 26624 : 34816;
    const i32x4* src = (const i32x4*)(exG + (size_t)j*stride);
    i32x4* dst = (i32x4*)exS;
    for (int i = tid; i < nv; i += 256) dst[i] = src[i];
  }
  if (tid < 192) {
    int local = tid/3, c = tid - (tid/3)*3;
    int row = (local>>4)*400 + j*16 + (local&15);
    w3S[tid] = wihRaw[(size_t)row*wihStride + c];
  }
  if (tid < 64) {
    int row = (tid>>4)*400 + j*16 + (tid&15);
    biasS[tid] = biasL[row];
  }
  for (int i = tid; i < 1024; i += 256) cL[i] = h0g[L*800 + 400 + j*16 + (i>>6)];
  __syncthreads();

  for (int t = 1; t <= TD; ++t) {
    // ---- waits ----
    if (wv == 0) {
      if constexpr (L > 0) waitflags2(fDep, nDep, (unsigned)t, nullptr, 0, 0u);
      if constexpr (LOC)   waitloc(flgS, NBL, (unsigned)(t-1));
      else                 waitflags2(fSelf, NBL, (unsigned)(t-1), nullptr, 0, 0u);
    }
    __syncthreads();

    // ---- issue cooperative staging copies (coalesced contiguous chunks) ----
    if constexpr (LOC && L > 0) {
      const i32x4* srcH = (const i32x4*)(hb_prev + (size_t)t*B_*HP);
      i32x4*       dstH = (i32x4*)(pin + (size_t)(t&1)*B_*HP);
      const i32x4* srcW = (const i32x4*)(wbf + (size_t)(t-1)*B_*ENC);
      i32x4*       dstW = (i32x4*)(win + (size_t)(t&1)*B_*ENC);
      int ih = j*134 + tid;
      if (tid < 134 && ih < 3328) dstH[ih] = srcH[ih];
      int iw = j*41 + (tid - 134);
      if (tid >= 134 && tid < 175 && iw < 1024) dstW[iw] = srcW[iw];
    }

    // ---- part-1: self-h loads + MFMAs (overlaps staging copies) ----
    const u16* hbase; const u16* lbase = nullptr;
    if constexpr (LOC) {
      hbase = hloc + (size_t)((t-1)&1)*B_*HP + kg*8;
      if constexpr (L==0) lbase = lloc + (size_t)((t-1)&1)*B_*HP + kg*8;
    } else {
      hbase = hb_self + (size_t)(t-1)*B_*HP + kg*8;
      if constexpr (L==0) lbase = hlo_ + (size_t)(t-1)*B_*HP + kg*8;
    }
    bf16x8 bh[4][4], bl[4][4];
    #pragma unroll
    for (int i=0;i<4;++i){
      int kt = wv + i*4;
      if (kt < KT_H) {
        #pragma unroll
        for (int nt=0;nt<4;++nt){
          if constexpr (LOC) bh[i][nt] = vld8(hbase + (size_t)(nt*16+col)*HP + kt*32);
          else               bh[i][nt] = *(const bf16x8*)(hbase + (size_t)(nt*16+col)*HP + kt*32);
          if constexpr (L==0) {
            if constexpr (LOC) bl[i][nt] = vld8(lbase + (size_t)(nt*16+col)*HP + kt*32);
            else               bl[i][nt] = *(const bf16x8*)(lbase + (size_t)(nt*16+col)*HP + kt*32);
          }
        }
      }
    }
    f32x4 acc[4][4];
    #pragma unroll
    for (int mt=0;mt<4;++mt)
      #pragma unroll
      for (int nt=0;nt<4;++nt){ f32x4 z = {0.f,0.f,0.f,0.f}; acc[mt][nt] = z; }
    #pragma unroll
    for (int i=0;i<4;++i){
      int kt = wv + i*4;
      if (kt < KT_H) {
        #pragma unroll
        for (int mt=0;mt<4;++mt){
          bf16x8 a = ahi[mt][i];
          #pragma unroll
          for (int nt=0;nt<4;++nt)
            acc[mt][nt] = __builtin_amdgcn_mfma_f32_16x16x32_bf16(a, bh[i][nt], acc[mt][nt], 0,0,0);
          if constexpr (L==0) {
            bf16x8 al = *(const bf16x8*)(exS + ((size_t)(mt*KT_H + kt)*64 + l)*8);
            #pragma unroll
            for (int nt=0;nt<4;++nt){
              acc[mt][nt] = __builtin_amdgcn_mfma_f32_16x16x32_bf16(a,  bl[i][nt], acc[mt][nt], 0,0,0);
              acc[mt][nt] = __builtin_amdgcn_mfma_f32_16x16x32_bf16(al, bh[i][nt], acc[mt][nt], 0,0,0);
            }
          }
        }
      }
    }

    // ---- part-2 (L>0): Wih @ [h_prevlayer[t] | w[t-1]] ----
    if constexpr (L > 0) {
      const u16* pbase; const u16* wbase;
      if constexpr (LOC) {
        // stage-flag round: copies drained -> publish -> wait all 25 staged
        __syncthreads();
        if (tid == 0) *((volatile unsigned*)(sgF + (size_t)j*CSTR)) = (unsigned)t;
        if (wv == 0) waitloc(sgF, NBL, (unsigned)t);
        __syncthreads();
        pbase = pin + (size_t)(t&1)*B_*HP + kg*8;
        wbase = win + (size_t)(t&1)*B_*ENC + kg*8;
      } else {
        pbase = hb_prev + (size_t)t*B_*HP + kg*8;
        wbase = wbf + ((size_t)(t-1)*B_)*ENC + kg*8;
      }
      bf16x8 pf[5][4];
      #pragma unroll
      for (int i=0;i<5;++i){
        int ktf = wv + i*4;
        if (ktf < 17) {
          #pragma unroll
          for (int nt=0;nt<4;++nt){
            if (ktf < 13) {
              if constexpr (LOC) pf[i][nt] = vld8(pbase + (size_t)(nt*16+col)*HP + ktf*32);
              else               pf[i][nt] = *(const bf16x8*)(pbase + (size_t)(nt*16+col)*HP + ktf*32);
            } else {
              if constexpr (LOC) pf[i][nt] = vld8(wbase + (size_t)(nt*16+col)*ENC + (ktf-13)*32);
              else               pf[i][nt] = *(const bf16x8*)(wbase + (size_t)(nt*16+col)*ENC + (ktf-13)*32);
            }
          }
        }
      }
      #pragma unroll
      for (int i=0;i<5;++i){
        int ktf = wv + i*4;
        if (ktf < 17) {
          #pragma unroll
          for (int mt=0;mt<4;++mt){
            bf16x8 a = *(const bf16x8*)(exS + ((size_t)(mt*17 + ktf)*64 + l)*8);
            #pragma unroll
            for (int nt=0;nt<4;++nt)
              acc[mt][nt] = __builtin_amdgcn_mfma_f32_16x16x32_bf16(a, pf[i][nt], acc[mt][nt], 0,0,0);
          }
        }
      }
    }
    // dump partials
    #pragma unroll
    for (int mt=0;mt<4;++mt)
      #pragma unroll
      for (int nt=0;nt<4;++nt)
        #pragma unroll
        for (int r=0;r<4;++r)
          dumpS[wv*4160 + (mt*16 + kg*4 + r)*65 + nt*16 + col] = acc[mt][nt][r];
    __syncthreads();
    // gates
    {
      const int bg = tid & 63, uq = tid >> 6;
      const float* sp = strokesT + ((size_t)(t-1)*B_ + bg)*4;
      float sx = sp[0], sy = sp[1], sz = sp[2];
      u16x4 hh4, ll4;
      #pragma unroll
      for (int e=0;e<4;++e){
        int u = uq*4 + e;
        int idx = u*64 + bg;
        float gv[4];
        #pragma unroll
        for (int g=0; g<4; ++g){
          int row = g*16 + u;
          float s = dumpS[row*65 + bg] + dumpS[4160 + row*65 + bg]
                  + dumpS[8320 + row*65 + bg] + dumpS[12480 + row*65 + bg];
          s += biasS[row] + w3S[row*3+0]*sx + w3S[row*3+1]*sy + w3S[row*3+2]*sz;
          gv[g] = s;
        }
        float co = cL[idx];
        float i_ = sigm(gv[0]), f_ = sigm(gv[1]), g_ = tanh_(gv[2]), o_ = sigm(gv[3]);
        float cn = f_*co + i_*g_;
        cL[idx] = cn;
        float hv = o_*tanh_(cn);
        u16 hh = f2b(hv);
        hh4[e] = hh;
        if constexpr (L==0) ll4[e] = f2b(hv - b2f(hh));
      }
      if constexpr (LOC) {
        *(u16x4*)(hloc + ((size_t)(t&1)*B_ + bg)*HP + j*16 + uq*4) = hh4;
        if constexpr (L==0) *(u16x4*)(lloc + ((size_t)(t&1)*B_ + bg)*HP + j*16 + uq*4) = ll4;
        if constexpr (L==2) {
          *(u16x4*)(hb_self + ((size_t)t*B_ + bg)*HP + j*16 + uq*4) = hh4;
        } else {
          st8(hb_self + ((size_t)t*B_ + bg)*HP + j*16 + uq*4, hh4);
          if constexpr (L==0) st8(hlo_ + ((size_t)t*B_ + bg)*HP + j*16 + uq*4, ll4);
        }
      } else {
        st8(hb_self + ((size_t)t*B_ + bg)*HP + j*16 + uq*4, hh4);
        if constexpr (L==0) st8(hlo_ + ((size_t)t*B_ + bg)*HP + j*16 + uq*4, ll4);
      }
    }
    __syncthreads();   // drains stores before flags
    if (tid == 0) {
      if constexpr (LOC) *((volatile unsigned*)(flgS + (size_t)j*CSTR)) = (unsigned)t;
      setflag(fSelf + (size_t)j*CSTR, (unsigned)t);
    }
  }
}

// ---------------- attention stage ----------------
DI void stage_attn(char* smem, int j2,
    const float* __restrict__ ctx, const float* __restrict__ cmask,
    const float* __restrict__ attnW, const float* __restrict__ attnB,
    const u16* __restrict__ hb0, const u16* __restrict__ hlo_,
    u16* __restrict__ wbf,
    const unsigned* __restrict__ fA, unsigned* __restrict__ fB)
{
  float* ctxS = (float*)(smem + ALDS_CTX);
  float* atwS = (float*)(smem + ALDS_ATW);
  float* hS   = (float*)(smem + ALDS_H);
  float* phiS = (float*)(smem + ALDS_PHI);
  float* mskS = (float*)(smem + ALDS_MSK);
  float* kapS = (float*)(smem + ALDS_KAP);
  float* pS   = (float*)(smem + ALDS_P);
  float* ppsS = (float*)(smem + ALDS_PPS);
  const int tid = threadIdx.x;
  const int b0 = j2*2;
  for (int i = tid; i < 2*80*128; i += 256) {
    int bi = i/10240, rem = i%10240;
    ctxS[i] = ctx[(size_t)(b0+bi)*10240 + rem];
  }
  for (int i = tid; i < 30*400; i += 256) {
    int row = i/400, k = i - row*400;
    atwS[row*401 + k] = attnW[i];
  }
  for (int i = tid; i < 160; i += 256) {
    int bi = i/80, u = i - bi*80;
    mskS[i] = cmask[(b0+bi)*80 + u];
  }
  if (tid < 20) kapS[tid] = 0.f;
  float aB = (tid < 60) ? attnB[tid % 30] : 0.f;
  __syncthreads();

  for (int t = 1; t <= TD; ++t) {
    if ((tid>>6) == 0) waitflags2(fA, NBL, (unsigned)t, nullptr, 0, 0u);
    __syncthreads();
    if (tid < 200) {
      int bi = tid/100, k = (tid%100)*4;
      size_t off = ((size_t)t*B_ + (b0+bi))*HP + k;
      u16x4 hi4 = *(const u16x4*)(hb0 + off);
      u16x4 lo4 = *(const u16x4*)(hlo_ + off);
      #pragma unroll
      for (int e=0;e<4;++e) hS[bi*400 + k + e] = b2f(hi4[e]) + b2f(lo4[e]);
    }
    __syncthreads();
    if (tid < 240) {
      int bi = tid/120, r = tid - bi*120;
      int row = r>>2, seg = r&3;
      const float* ar = atwS + row*401 + seg*100;
      const float* hr = hS + bi*400 + seg*100;
      float a0=0,a1=0,a2=0,a3=0;
      #pragma unroll 4
      for (int k=0;k<100;k+=4){
        a0 += ar[k]*hr[k]; a1 += ar[k+1]*hr[k+1];
        a2 += ar[k+2]*hr[k+2]; a3 += ar[k+3]*hr[k+3];
      }
      ppsS[(bi*30+row)*4+seg] = a0+a1+a2+a3;
    }
    __syncthreads();
    if (tid < 60) {
      int bi = tid/30, row = tid - bi*30;
      const float* pp = ppsS + (bi*30+row)*4;
      pS[bi*30+row] = __expf(pp[0]+pp[1]+pp[2]+pp[3] + aB);
    }
    __syncthreads();
    if (tid < 20) {
      int bi = tid/10, m = tid - bi*10;
      kapS[tid] += 0.2f * pS[bi*30 + 20 + m];
    }
    __syncthreads();
    if (tid < 160) {
      int bi = tid/80; float u2 = (float)(tid - bi*80);
      const float* pb = pS + bi*30; const float* kb = kapS + bi*10;
      float a = 0.f;
      #pragma unroll
      for (int m=0;m<10;++m){ float d = kb[m]-u2; a += pb[m]*__expf(-pb[10+m]*d*d); }
      phiS[tid] = a * mskS[tid];
    }
    __syncthreads();
    {
      int bi = tid >> 7, e = tid & 127;
      const float* ph = phiS + bi*80;
      const float* cs = ctxS + (size_t)bi*10240 + e;
      float a = 0.f;
      for (int u = 0; u < TC; ++u) a += ph[u]*cs[u*128];
      st16(wbf + ((size_t)(t-1)*B_ + (b0+bi))*ENC + e, f2b(a));
    }
    __syncthreads();
    if (tid == 0) setflag(fB + (size_t)j2*CSTR, (unsigned)t);
  }
}

// ---------------- xcc uniformity check ----------------
DI bool xcc_check(char* smem, int stage, int j, unsigned* xccb){
  unsigned* xs = xccb + (size_t)stage*FSLOT*CSTR;
  if (threadIdx.x == 0) setflag(xs + (size_t)j*CSTR, 0x100u | (unsigned)get_xcc());
  if ((threadIdx.x>>6) == 0) {
    waitflags2(xs, NBL, 0x100u, nullptr, 0, 0u);
    int lane = threadIdx.x & 63;
    unsigned v = __hip_atomic_load(xs + (size_t)((lane<NBL)?lane:0)*CSTR,
                                   __ATOMIC_RELAXED, __HIP_MEMORY_SCOPE_AGENT);
    unsigned r0 = __shfl(v, 0);
    int uni = __all(v == r0) ? 1 : 0;
    if (threadIdx.x == 0) *(int*)(smem + LDS_VERD) = uni;
  }
  __syncthreads();
  return (*(int*)(smem + LDS_VERD)) != 0;
}

// ---------------- mega kernel ----------------
__global__ __launch_bounds__(256,1) void k_mega(
    const u16* apkH, const u16* apkL, const u16* wf1, const u16* wf2,
    const float* strokesT, const float* Wih0, const float* Wih1, const float* Wih2,
    const float* bia, const float* h0g,
    u16* hb0, u16* hb1, u16* hb2, u16* hlo, u16* wbf,
    const float* ctx, const float* cmask, const float* attnW, const float* attnB,
    unsigned* cnt, unsigned* xccb, unsigned* flgb,
    u16* hl0, u16* ll0, u16* hl1, u16* hl2,
    u16* pi1, u16* wi1, u16* pi2, u16* wi2)
{
  extern __shared__ char smem[];
  unsigned* fA = cnt;
  unsigned* fB = cnt + (size_t)FSLOT*CSTR;
  unsigned* fC = cnt + (size_t)2*FSLOT*CSTR;
  unsigned* fD = cnt + (size_t)3*FSLOT*CSTR;
  int b = blockIdx.x; int colx = b & 7; int row = b >> 3;
  if (colx == 0 && row < NBL) {
    bool loc = xcc_check(smem, 0, row, xccb);
    if (loc) stage_lstm<0,true >(smem, row, apkH, apkL, strokesT, Wih0, 3, bia, h0g,
                  hb0, nullptr, hlo, nullptr, fA, nullptr, 0, hl0, ll0, flgb,
                  nullptr, nullptr, nullptr);
    else     stage_lstm<0,false>(smem, row, apkH, apkL, strokesT, Wih0, 3, bia, h0g,
                  hb0, nullptr, hlo, nullptr, fA, nullptr, 0, hl0, ll0, flgb,
                  nullptr, nullptr, nullptr);
  } else if ((colx == 1 || colx == 2) && row < 16) {
    int j2 = (colx-1)*16 + row;
    stage_attn(smem, j2, ctx, cmask, attnW, attnB, hb0, hlo, wbf, fA, fB);
  } else if (colx == 3 && row < NBL) {
    bool loc = xcc_check(smem, 1, row, xccb);
    unsigned* fg = flgb + (size_t)FSLOT*CSTR;
    unsigned* sg = flgb + (size_t)3*FSLOT*CSTR;
    if (loc) stage_lstm<1,true >(smem, row, apkH + (size_t)1*NBL*26624, wf1, strokesT, Wih1, 531,
                  bia+1600, h0g, hb1, hb0, nullptr, wbf, fC, fB, NBA, hl1, nullptr, fg,
                  pi1, wi1, sg);
    else     stage_lstm<1,false>(smem, row, apkH + (size_t)1*NBL*26624, wf1, strokesT, Wih1, 531,
                  bia+1600, h0g, hb1, hb0, nullptr, wbf, fC, fB, NBA, hl1, nullptr, fg,
                  pi1, wi1, sg);
  } else if (colx == 4 && row < NBL) {
    bool loc = xcc_check(smem, 2, row, xccb);
    unsigned* fg = flgb + (size_t)2*FSLOT*CSTR;
    unsigned* sg = flgb + (size_t)4*FSLOT*CSTR;
    if (loc) stage_lstm<2,true >(smem, row, apkH + (size_t)2*NBL*26624, wf2, strokesT, Wih2, 531,
                  bia+3200, h0g, hb2, hb1, nullptr, wbf, fD, fC, NBL, hl2, nullptr, fg,
                  pi2, wi2, sg);
    else     stage_lstm<2,false>(smem, row, apkH + (size_t)2*NBL*26624, wf2, strokesT, Wih2, 531,
                  bia+3200, h0g, hb2, hb1, nullptr, wbf, fD, fC, NBL, hl2, nullptr, fg,
                  pi2, wi2, sg);
  }
}

// ---------------- output projection -> f32 d_out ----------------
__global__ __launch_bounds__(256) void k_gemm_out(const u16* __restrict__ hb0, const u16* __restrict__ hb1,
                                                  const u16* __restrict__ hb2, const u16* __restrict__ ouw,
                                                  const float* __restrict__ out_b, float* __restrict__ dout){
  int wv = threadIdx.x>>6, l = threadIdx.x&63;
  int task = blockIdx.x*4 + wv;
  int ng = task & 1; int mpair = task >> 1;
  int m0 = mpair*32; int t = m0>>6; int broff = m0 & 63;
  int col = l&15, kg = l>>4;
  f32x4 acc[2][4];
  #pragma unroll
  for (int mt=0;mt<2;++mt)
    #pragma unroll
    for (int nt=0;nt<4;++nt){ f32x4 z = {0.f,0.f,0.f,0.f}; acc[mt][nt] = z; }
  for (int kt=0; kt<38; ++kt) {
    int k0 = kt*32 + kg*8;
    int reg = (k0>=800) ? 2 : ((k0>=400) ? 1 : 0);
    int koff = k0 - reg*400;
    const u16* hb = (reg==0) ? hb0 : ((reg==1) ? hb1 : hb2);
    bf16x8 afr[2];
    #pragma unroll
    for (int mt=0;mt<2;++mt)
      afr[mt] = *(const bf16x8*)(hb + ((size_t)(t+1)*B_ + broff + mt*16 + col)*HP + koff);
    #pragma unroll
    for (int nt=0;nt<4;++nt) {
      bf16x8 bfr = *(const bf16x8*)(ouw + (size_t)(ng*64 + nt*16 + col)*KOP + k0);
      #pragma unroll
      for (int mt=0;mt<2;++mt)
        acc[mt][nt] = __builtin_amdgcn_mfma_f32_16x16x32_bf16(afr[mt], bfr, acc[mt][nt], 0,0,0);
    }
  }
  #pragma unroll
  for (int mt=0;mt<2;++mt)
    #pragma unroll
    for (int nt=0;nt<4;++nt)
      #pragma unroll
      for (int r=0;r<4;++r) {
        int n = ng*64 + nt*16 + col;
        int bo = broff + mt*16 + kg*4 + r;
        if (n < OUTN) dout[((size_t)bo*TD + t)*OUTN + n] = acc[mt][nt][r] + out_b[n];
      }
}

__global__ void k_sentinel(float* o, float code){ o[threadIdx.x] = code; }

// ---------------- host ----------------
extern "C" void kernel_launch(void* const* d_in, const int* in_sizes, int n_in,
                              void* d_out, int out_size, void* d_ws, size_t ws_size,
                              hipStream_t stream) {
  const float* strokes = (const float*)d_in[0];
  const float* context = (const float*)d_in[1];
  const float* cmask   = (const float*)d_in[2];
  const float* h0      = (const float*)d_in[3];
  const float* Wih0 = (const float*)d_in[4];  const float* Whh0 = (const float*)d_in[5];
  const float* bih0 = (const float*)d_in[6];  const float* bhh0 = (const float*)d_in[7];
  const float* Wih1 = (const float*)d_in[8];  const float* Whh1 = (const float*)d_in[9];
  const float* bih1 = (const float*)d_in[10]; const float* bhh1 = (const float*)d_in[11];
  const float* Wih2 = (const float*)d_in[12]; const float* Whh2 = (const float*)d_in[13];
  const float* bih2 = (const float*)d_in[14]; const float* bhh2 = (const float*)d_in[15];
  const float* attnW = (const float*)d_in[16]; const float* attnB = (const float*)d_in[17];
  const float* outW  = (const float*)d_in[18]; const float* outB  = (const float*)d_in[19];
  float* dout = (float*)d_out;

  if (ws_size < WS_NEED) {
    float code = 1000.0f + (float)(ws_size >> 20);
    k_sentinel<<<1, 64, 0, stream>>>(dout, code);
    return;
  }

  char* ws = (char*)d_ws;
  u16* hb0 = (u16*)(ws + OFF_HB0);
  u16* hb1 = (u16*)(ws + OFF_HB1);
  u16* hb2 = (u16*)(ws + OFF_HB2);
  u16* hlo = (u16*)(ws + OFF_HLO);
  u16* wbf = (u16*)(ws + OFF_WBF);
  float* strT = (float*)(ws + OFF_STR);
  u16* apkH = (u16*)(ws + OFF_APKH);
  u16* apkL = (u16*)(ws + OFF_APKL);
  u16* wf1  = (u16*)(ws + OFF_WF1);
  u16* wf2  = (u16*)(ws + OFF_WF2);
  u16* ouw  = (u16*)(ws + OFF_OUW);
  float* bia = (float*)(ws + OFF_BIA);
  unsigned* cnt = (unsigned*)(ws + OFF_CNT);
  unsigned* xccb = (unsigned*)(ws + OFF_XCC);
  unsigned* flgb = (unsigned*)(ws + OFF_FLG);
  u16* hl0 = (u16*)(ws + OFF_HL0);
  u16* ll0 = (u16*)(ws + OFF_LL0);
  u16* hl1 = (u16*)(ws + OFF_HL1);
  u16* hl2 = (u16*)(ws + OFF_HL2);
  u16* pi1 = (u16*)(ws + OFF_PI1);
  u16* wi1 = (u16*)(ws + OFF_WI1);
  u16* pi2 = (u16*)(ws + OFF_PI2);
  u16* wi2 = (u16*)(ws + OFF_WI2);

  (void)hipFuncSetAttribute((const void*)k_mega, hipFuncAttributeMaxDynamicSharedMemorySize, LDSB);

  {
    int n = 3*B_*HP + B_*HP + 4*TD*B_*16 + 4*FSLOT + 8*FSLOT + 4*2*B_*HP;
    k_init<<<(n+255)/256, 256, 0, stream>>>(h0, hb0, hb1, hb2, hlo, cnt, xccb, flgb, hl0, ll0, hl1, hl2);
  }
  k_apack<<<(3*NBL*4*KT_H*64+255)/256, 256, 0, stream>>>(Whh0, Whh1, Whh2, apkH, apkL);
  k_wihpack2<<<(NBL*4*17*64+255)/256, 256, 0, stream>>>(Wih1, wf1);
  k_wihpack2<<<(NBL*4*17*64+255)/256, 256, 0, stream>>>(Wih2, wf2);
  {
    int n = NOP*KOP + 3*1600;
    k_smallpack<<<(n+255)/256, 256, 0, stream>>>(outW, bih0,bhh0,bih1,bhh1,bih2,bhh2, ouw, bia);
  }
  k_packs<<<(TD*B_+255)/256, 256, 0, stream>>>(strokes, strT);

  // ---- fused pipelined recurrence (256-block grid, XCD-column layout) ----
  k_mega<<<256, 256, LDSB, stream>>>(apkH, apkL, wf1, wf2,
      strT, Wih0, Wih1, Wih2, bia, h0,
      hb0, hb1, hb2, hlo, wbf,
      context, cmask, attnW, attnB, cnt, xccb, flgb, hl0, ll0, hl1, hl2,
      pi1, wi1, pi2, wi2);

  // ---- output projection ----
  k_gemm_out<<<3200/4, 256, 0, stream>>>(hb0, hb1, hb2, ouw, outB, dout);
}

// Round 17
// 7304.197 us; speedup vs baseline: 1.1950x; 1.1698x over previous
//
#include <hip/hip_runtime.h>
#include <stdint.h>

typedef unsigned short u16;
typedef __attribute__((ext_vector_type(8))) short bf16x8;
typedef __attribute__((ext_vector_type(4))) float f32x4;
typedef __attribute__((ext_vector_type(4))) int   i32x4;
typedef __attribute__((ext_vector_type(4))) unsigned short u16x4;

#define DI static __device__ __forceinline__

constexpr int B_   = 64;
constexpr int TD   = 800;
constexpr int TC   = 80;
constexpr int ENC  = 128;
constexpr int H    = 400;
constexpr int OUTN = 121;

constexpr int HP   = 416;
constexpr int KT_H = 13;
constexpr int KOP  = 1216;
constexpr int NOP  = 128;
constexpr int NBL  = 25;
constexpr int NBA  = 32;
constexpr int CSTR = 32;
constexpr int FSLOT= 32;

// ---------------- workspace layout ----------------
constexpr size_t HB_B  = (size_t)(TD+1)*B_*HP*2;
constexpr size_t WBF_B = (size_t)TD*B_*ENC*2;
constexpr size_t STR_B = (size_t)TD*B_*4*4;
constexpr size_t APK_B = (size_t)NBL*4*KT_H*64*8*2;
constexpr size_t WF_B  = (size_t)NBL*4*17*64*8*2;
constexpr size_t LOC_B = (size_t)2*B_*HP*2;

constexpr size_t OFF_HB0 = 0;
constexpr size_t OFF_HB1 = OFF_HB0 + HB_B;
constexpr size_t OFF_HB2 = OFF_HB1 + HB_B;
constexpr size_t OFF_HLO = OFF_HB2 + HB_B;
constexpr size_t OFF_WBF = OFF_HLO + HB_B;
constexpr size_t OFF_STR = OFF_WBF + WBF_B;
constexpr size_t OFF_APKH= OFF_STR + STR_B;
constexpr size_t OFF_APKL= OFF_APKH + 3*APK_B;
constexpr size_t OFF_WF1 = OFF_APKL + APK_B;
constexpr size_t OFF_WF2 = OFF_WF1 + WF_B;
constexpr size_t OFF_OUW = OFF_WF2 + WF_B;
constexpr size_t OFF_BIA = OFF_OUW + (size_t)NOP*KOP*2;
constexpr size_t OFF_CNT = OFF_BIA + (size_t)3*1600*4;
constexpr size_t OFF_XCC = OFF_CNT + (size_t)4*FSLOT*CSTR*4;
constexpr size_t OFF_FLG = OFF_XCC + (size_t)3*FSLOT*CSTR*4;
constexpr size_t OFF_HL0 = OFF_FLG + (size_t)3*FSLOT*CSTR*4;
constexpr size_t OFF_LL0 = OFF_HL0 + LOC_B;
constexpr size_t OFF_HL1 = OFF_LL0 + LOC_B;
constexpr size_t OFF_HL2 = OFF_HL1 + LOC_B;
constexpr size_t WS_NEED = OFF_HL2 + LOC_B + 256;

// LDS offsets
constexpr int LDS_DUMP = 0;
constexpr int LDS_CL   = 66560;
constexpr int LDS_EX   = 70656;
constexpr int LDS_W3   = 140288;
constexpr int LDS_BIAS = 141056;
constexpr int LDS_VERD = 141312;
constexpr int LDSB     = 141568;
constexpr int ALDS_CTX = 0;
constexpr int ALDS_ATW = 81920;
constexpr int ALDS_H   = 130040;
constexpr int ALDS_PHI = 133240;
constexpr int ALDS_MSK = 133880;
constexpr int ALDS_KAP = 134520;
constexpr int ALDS_P   = 134600;
constexpr int ALDS_PPS = 134840;

DI u16 f2b(float f){ union{float f; unsigned u;} v; v.f=f; unsigned r = v.u + 0x7FFFu + ((v.u>>16)&1u); return (u16)(r>>16); }
DI float b2f(u16 h){ union{unsigned u; float f;} v; v.u=((unsigned)h)<<16; return v.f; }
DI float sigm(float x){ return 1.f/(1.f+__expf(-x)); }
DI float tanh_(float x){ float a=fabsf(x), e=__expf(-2.f*a), t=(1.f-e)/(1.f+e); return x<0.f ? -t : t; }

// LLC-coherent stores (write-through past L2)
DI void st16(u16* p, u16 v){
  asm volatile("global_store_short %0, %1, off sc0 sc1" :: "v"(p), "v"((unsigned)v) : "memory");
}
DI void st8(u16* p, u16x4 v){
  unsigned long long x; __builtin_memcpy(&x, &v, 8);
  asm volatile("global_store_dwordx2 %0, %1, off sc0 sc1" :: "v"(p), "v"(x) : "memory");
}
DI void setflag(unsigned* p, unsigned t){
  asm volatile("global_store_dword %0, %1, off sc0 sc1" :: "v"(p), "v"(t) : "memory");
}
// LLC flag wait (relaxed gather)
DI void waitflags2(const unsigned* fA, int nA, unsigned tA,
                   const unsigned* fB, int nB, unsigned tB){
  int lane = threadIdx.x & 63;
  const unsigned* p; unsigned tgt;
  if (lane < nA)            { p = fA + (size_t)lane*CSTR;        tgt = tA; }
  else if (lane < nA+nB)    { p = fB + (size_t)(lane-nA)*CSTR;   tgt = tB; }
  else                      { p = fA;                            tgt = 0;  }
  while (1) {
    unsigned v = __hip_atomic_load(p, __ATOMIC_RELAXED, __HIP_MEMORY_SCOPE_AGENT);
    if (__all(v >= tgt)) break;
    __builtin_amdgcn_s_sleep(1);
  }
  asm volatile("" ::: "memory");
}
// XCD-local flag wait: volatile loads (bypass L1, hit shared L2)
DI void waitloc(const unsigned* f, int n, unsigned tgt){
  int lane = threadIdx.x & 63;
  const volatile unsigned* p = (const volatile unsigned*)(f + (size_t)((lane<n)?lane:0)*CSTR);
  while (1) {
    unsigned v = *p;
    if (__all(v >= tgt)) break;
    __builtin_amdgcn_s_sleep(1);
  }
  asm volatile("" ::: "memory");
}
// volatile 16B load (bypass L1; address-reuse safe)
DI bf16x8 vld8(const u16* p){
  i32x4 v = *(const volatile i32x4*)p;
  bf16x8 r; __builtin_memcpy(&r, &v, 16); return r;
}
DI int get_xcc(){
  int x; asm volatile("s_getreg_b32 %0, hwreg(HW_REG_XCC_ID)" : "=s"(x)); return x & 0xff;
}

// ---------------- init ----------------
__global__ void k_init(const float* __restrict__ h0, u16* hb0, u16* hb1, u16* hb2, u16* hlo,
                       unsigned* cnt, unsigned* xccb, unsigned* flgb,
                       u16* hl0, u16* ll0, u16* hl1, u16* hl2){
  int i = blockIdx.x*256 + threadIdx.x;
  const int nA = 3*B_*HP, nA2 = B_*HP, nB = 4*TD*B_*16, nC = 4*FSLOT, nD = 6*FSLOT;
  const int nE = 4*2*B_*HP;
  if (i < nA) {
    int l = i/(B_*HP); int rem = i - l*(B_*HP); int b = rem/HP; int k = rem - b*HP;
    u16 v = (k<H) ? f2b(h0[l*800 + k]) : (u16)0;
    (l==0?hb0:(l==1?hb1:hb2))[(size_t)b*HP + k] = v;
  } else if (i < nA+nA2) {
    int rem = i - nA; int b = rem/HP; int k = rem - b*HP;
    u16 v = 0;
    if (k < H) { float w = h0[k]; u16 hi = f2b(w); v = f2b(w - b2f(hi)); }
    hlo[(size_t)b*HP + k] = v;
  } else if (i < nA+nA2+nB) {
    int q = i - nA - nA2; int buf = q/(TD*B_*16); int r2 = q % (TD*B_*16);
    int t = r2/(B_*16) + 1; int r3 = r2 % (B_*16); int b = r3>>4; int kk = r3&15;
    u16* hb = (buf==0)?hb0:((buf==1)?hb1:((buf==2)?hb2:hlo));
    hb[((size_t)t*B_ + b)*HP + 400 + kk] = 0;
  } else if (i < nA+nA2+nB+nC) {
    int q = i - nA - nA2 - nB;
    cnt[(size_t)q*CSTR] = 0u;
  } else if (i < nA+nA2+nB+nC+nD) {
    int q = i - nA - nA2 - nB - nC;
    if (q < 3*FSLOT) xccb[(size_t)q*CSTR] = 0u;
    else             flgb[(size_t)(q-3*FSLOT)*CSTR] = 0u;
  } else if (i < nA+nA2+nB+nC+nD+nE) {
    int q = i - nA - nA2 - nB - nC - nD;
    int buf = q / (2*B_*HP); int rem = q % (2*B_*HP);
    int k = rem % HP;
    u16 v = 0;
    if (k < H) {
      if (buf == 0)      v = f2b(h0[k]);
      else if (buf == 1) { float w = h0[k]; u16 hi = f2b(w); v = f2b(w - b2f(hi)); }
      else if (buf == 2) v = f2b(h0[800 + k]);
      else               v = f2b(h0[1600 + k]);
    }
    (buf==0?hl0:(buf==1?ll0:(buf==2?hl1:hl2)))[rem] = v;
  }
}

// ---------------- pack Whh: A-fragments hi (3 layers) + lo (layer 0) ----------------
__global__ void k_apack(const float* W0, const float* W1, const float* W2,
                        u16* apkHi, u16* apkLo){
  int i = blockIdx.x*256 + threadIdx.x;
  const int total = 3*NBL*4*KT_H*64;
  if (i >= total) return;
  int lane = i & 63; int r = i >> 6;
  int kt = r % KT_H; r /= KT_H;
  int mt = r % 4;    r /= 4;
  int j  = r % NBL;  int lv = r / NBL;
  const float* W = (lv==0)?W0:((lv==1)?W1:W2);
  int row = mt*400 + j*16 + (lane & 15);
  int kbase = kt*32 + (lane>>4)*8;
  #pragma unroll
  for (int e=0;e<8;++e){
    int k = kbase+e;
    float w = (k<H) ? W[(size_t)row*H + k] : 0.f;
    u16 hi = f2b(w);
    apkHi[(size_t)i*8 + e] = hi;
    if (lv == 0) apkLo[(size_t)i*8 + e] = f2b(w - b2f(hi));
  }
}

// ---------------- pack Wih1/2 cols 3..530 into per-block A-fragments ----------------
__global__ void k_wihpack2(const float* __restrict__ W, u16* __restrict__ dst){
  int i = blockIdx.x*256 + threadIdx.x;
  if (i >= NBL*4*17*64) return;
  int lane = i & 63; int r = i >> 6;
  int ktf = r % 17; r /= 17; int mt = r % 4; int j = r / 4;
  int row = mt*400 + j*16 + (lane & 15);
  int kbase = ktf*32 + (lane>>4)*8;
  #pragma unroll
  for (int e=0;e<8;++e){
    int k = kbase+e;
    int col;
    if (ktf < 13) col = (k < 400) ? (3 + k) : -1;
    else          col = 403 + (k - 416);
    dst[(size_t)i*8 + e] = (col >= 0) ? f2b(W[(size_t)row*531 + col]) : (u16)0;
  }
}

// ---------------- pack out_W + biases ----------------
__global__ void k_smallpack(const float* outW,
                            const float* bi0, const float* bh0, const float* bi1, const float* bh1,
                            const float* bi2, const float* bh2,
                            u16* ouw, float* biasP){
  int i = blockIdx.x*256 + threadIdx.x;
  const int n2 = NOP*KOP, n3 = 3*1600;
  if (i < n2) {
    int n = i/KOP, k = i - n*KOP;
    ouw[i] = (n<OUTN && k<1200) ? f2b(outW[(size_t)n*1200 + k]) : (u16)0;
  } else if (i < n2+n3) {
    int q = i-n2; int l = q/1600, row = q - l*1600;
    const float* bi = (l==0)?bi0:((l==1)?bi1:bi2);
    const float* bh = (l==0)?bh0:((l==1)?bh1:bh2);
    biasP[q] = bi[row] + bh[row];
  }
}

// ---------------- strokes transpose: [t][b][4] f32 ----------------
__global__ void k_packs(const float* __restrict__ strokes, float* __restrict__ st){
  int i = blockIdx.x*256 + threadIdx.x;
  if (i >= TD*B_) return;
  int t = i / B_, b = i & 63;
  st[(size_t)i*4+0] = strokes[((size_t)b*TD + t)*3 + 0];
  st[(size_t)i*4+1] = strokes[((size_t)b*TD + t)*3 + 1];
  st[(size_t)i*4+2] = strokes[((size_t)b*TD + t)*3 + 2];
  st[(size_t)i*4+3] = 0.f;
}

// ---------------- LSTM stage (device function) ----------------
template<int L, bool LOC>
DI void stage_lstm(char* smem, int j,
    const u16* __restrict__ apkHi, const u16* __restrict__ exG,
    const float* __restrict__ strokesT,
    const float* __restrict__ wihRaw, int wihStride,
    const float* __restrict__ biasL, const float* __restrict__ h0g,
    u16* __restrict__ hb_self, const u16* __restrict__ hb_prev,
    u16* __restrict__ hlo_, const u16* __restrict__ wbf,
    unsigned* __restrict__ fSelf, const unsigned* __restrict__ fDep, int nDep,
    u16* __restrict__ hloc, u16* __restrict__ lloc, unsigned* __restrict__ flgS)
{
  float* dumpS = (float*)(smem + LDS_DUMP);
  float* cL    = (float*)(smem + LDS_CL);
  u16*   exS   = (u16*)  (smem + LDS_EX);
  float* w3S   = (float*)(smem + LDS_W3);
  float* biasS = (float*)(smem + LDS_BIAS);
  const int tid = threadIdx.x, wv = tid>>6, l = tid&63;
  const int col = l&15, kg = l>>4;

  bf16x8 ahi[4][4];
  #pragma unroll
  for (int mt=0;mt<4;++mt)
    #pragma unroll
    for (int i=0;i<4;++i){
      int kt = wv + i*4;
      if (kt < KT_H) ahi[mt][i] = *(const bf16x8*)(apkHi + (size_t)j*26624 + ((size_t)(mt*KT_H + kt)*64 + l)*8);
      else { bf16x8 z = {0,0,0,0,0,0,0,0}; ahi[mt][i] = z; }
    }
  {
    const int nv = (L==0) ? 3328 : 4352;
    const size_t stride = (L==0) ? 26624 : 34816;
    const i32x4* src = (const i32x4*)(exG + (size_t)j*stride);
    i32x4* dst = (i32x4*)exS;
    for (int i = tid; i < nv; i += 256) dst[i] = src[i];
  }
  if (tid < 192) {
    int local = tid/3, c = tid - (tid/3)*3;
    int row = (local>>4)*400 + j*16 + (local&15);
    w3S[tid] = wihRaw[(size_t)row*wihStride + c];
  }
  if (tid < 64) {
    int row = (tid>>4)*400 + j*16 + (tid&15);
    biasS[tid] = biasL[row];
  }
  for (int i = tid; i < 1024; i += 256) cL[i] = h0g[L*800 + 400 + j*16 + (i>>6)];
  __syncthreads();

  for (int t = 1; t <= TD; ++t) {
    if (wv == 0) {
      if constexpr (L > 0) waitflags2(fDep, nDep, (unsigned)t, nullptr, 0, 0u);
      if constexpr (LOC)   waitloc(flgS, NBL, (unsigned)(t-1));
      else                 waitflags2(fSelf, NBL, (unsigned)(t-1), nullptr, 0, 0u);
    }
    __syncthreads();
    f32x4 acc[4][4];
    #pragma unroll
    for (int mt=0;mt<4;++mt)
      #pragma unroll
      for (int nt=0;nt<4;++nt){ f32x4 z = {0.f,0.f,0.f,0.f}; acc[mt][nt] = z; }

    // part 1: Whh @ h_self[t-1]
    const u16* hbase; const u16* lbase = nullptr;
    if constexpr (LOC) {
      hbase = hloc + (size_t)((t-1)&1)*B_*HP + kg*8;
      if constexpr (L==0) lbase = lloc + (size_t)((t-1)&1)*B_*HP + kg*8;
    } else {
      hbase = hb_self + (size_t)(t-1)*B_*HP + kg*8;
      if constexpr (L==0) lbase = hlo_ + (size_t)(t-1)*B_*HP + kg*8;
    }
    #pragma unroll
    for (int i=0;i<4;++i){
      int kt = wv + i*4;
      if (kt < KT_H) {
        bf16x8 bhi[4], blo[4];
        #pragma unroll
        for (int nt=0;nt<4;++nt){
          if constexpr (LOC) bhi[nt] = vld8(hbase + (size_t)(nt*16+col)*HP + kt*32);
          else               bhi[nt] = *(const bf16x8*)(hbase + (size_t)(nt*16+col)*HP + kt*32);
          if constexpr (L==0) {
            if constexpr (LOC) blo[nt] = vld8(lbase + (size_t)(nt*16+col)*HP + kt*32);
            else               blo[nt] = *(const bf16x8*)(lbase + (size_t)(nt*16+col)*HP + kt*32);
          }
        }
        #pragma unroll
        for (int mt=0;mt<4;++mt){
          bf16x8 a = ahi[mt][i];
          #pragma unroll
          for (int nt=0;nt<4;++nt)
            acc[mt][nt] = __builtin_amdgcn_mfma_f32_16x16x32_bf16(a, bhi[nt], acc[mt][nt], 0,0,0);
          if constexpr (L==0) {
            bf16x8 al = *(const bf16x8*)(exS + ((size_t)(mt*KT_H + kt)*64 + l)*8);
            #pragma unroll
            for (int nt=0;nt<4;++nt){
              acc[mt][nt] = __builtin_amdgcn_mfma_f32_16x16x32_bf16(a,  blo[nt], acc[mt][nt], 0,0,0);
              acc[mt][nt] = __builtin_amdgcn_mfma_f32_16x16x32_bf16(al, bhi[nt], acc[mt][nt], 0,0,0);
            }
          }
        }
      }
    }
    // part 2 (L>0): Wih @ [h_prevlayer[t] | w[t-1]]  (LLC copies, unique addresses)
    if constexpr (L > 0) {
      const u16* pbase = hb_prev + (size_t)t*B_*HP + kg*8;
      const u16* wbase = wbf + ((size_t)(t-1)*B_)*ENC + kg*8;
      #pragma unroll
      for (int i=0;i<5;++i){
        int ktf = wv + i*4;
        if (ktf < 17) {
          bf16x8 bfr[4];
          if (ktf < 13) {
            #pragma unroll
            for (int nt=0;nt<4;++nt) bfr[nt] = *(const bf16x8*)(pbase + (size_t)(nt*16+col)*HP + ktf*32);
          } else {
            #pragma unroll
            for (int nt=0;nt<4;++nt) bfr[nt] = *(const bf16x8*)(wbase + (size_t)(nt*16+col)*ENC + (ktf-13)*32);
          }
          #pragma unroll
          for (int mt=0;mt<4;++mt){
            bf16x8 a = *(const bf16x8*)(exS + ((size_t)(mt*17 + ktf)*64 + l)*8);
            #pragma unroll
            for (int nt=0;nt<4;++nt)
              acc[mt][nt] = __builtin_amdgcn_mfma_f32_16x16x32_bf16(a, bfr[nt], acc[mt][nt], 0,0,0);
          }
        }
      }
    }
    // dump partials
    #pragma unroll
    for (int mt=0;mt<4;++mt)
      #pragma unroll
      for (int nt=0;nt<4;++nt)
        #pragma unroll
        for (int r=0;r<4;++r)
          dumpS[wv*4160 + (mt*16 + kg*4 + r)*65 + nt*16 + col] = acc[mt][nt][r];
    __syncthreads();
    // gates
    {
      const int bg = tid & 63, uq = tid >> 6;
      const float* sp = strokesT + ((size_t)(t-1)*B_ + bg)*4;
      float sx = sp[0], sy = sp[1], sz = sp[2];
      u16x4 hh4, ll4;
      #pragma unroll
      for (int e=0;e<4;++e){
        int u = uq*4 + e;
        int idx = u*64 + bg;
        float gv[4];
        #pragma unroll
        for (int g=0; g<4; ++g){
          int row = g*16 + u;
          float s = dumpS[row*65 + bg] + dumpS[4160 + row*65 + bg]
                  + dumpS[8320 + row*65 + bg] + dumpS[12480 + row*65 + bg];
          s += biasS[row] + w3S[row*3+0]*sx + w3S[row*3+1]*sy + w3S[row*3+2]*sz;
          gv[g] = s;
        }
        float co = cL[idx];
        float i_ = sigm(gv[0]), f_ = sigm(gv[1]), g_ = tanh_(gv[2]), o_ = sigm(gv[3]);
        float cn = f_*co + i_*g_;
        cL[idx] = cn;
        float hv = o_*tanh_(cn);
        u16 hh = f2b(hv);
        hh4[e] = hh;
        if constexpr (L==0) ll4[e] = f2b(hv - b2f(hh));
      }
      if constexpr (LOC) {
        *(u16x4*)(hloc + ((size_t)(t&1)*B_ + bg)*HP + j*16 + uq*4) = hh4;
        if constexpr (L==0) *(u16x4*)(lloc + ((size_t)(t&1)*B_ + bg)*HP + j*16 + uq*4) = ll4;
      }
      st8(hb_self + ((size_t)t*B_ + bg)*HP + j*16 + uq*4, hh4);
      if constexpr (L==0) st8(hlo_ + ((size_t)t*B_ + bg)*HP + j*16 + uq*4, ll4);
    }
    __syncthreads();   // drains all stores (local in L2, sc1 in LLC)
    if (tid == 0) {
      if constexpr (LOC) *((volatile unsigned*)(flgS + (size_t)j*CSTR)) = (unsigned)t;
      setflag(fSelf + (size_t)j*CSTR, (unsigned)t);
    }
  }
}

// ---------------- attention stage (2 batches per block) ----------------
DI void stage_attn(char* smem, int j2,
    const float* __restrict__ ctx, const float* __restrict__ cmask,
    const float* __restrict__ attnW, const float* __restrict__ attnB,
    const u16* __restrict__ hb0, const u16* __restrict__ hlo_,
    u16* __restrict__ wbf,
    const unsigned* __restrict__ fA, unsigned* __restrict__ fB)
{
  float* ctxS = (float*)(smem + ALDS_CTX);
  float* atwS = (float*)(smem + ALDS_ATW);
  float* hS   = (float*)(smem + ALDS_H);
  float* phiS = (float*)(smem + ALDS_PHI);
  float* mskS = (float*)(smem + ALDS_MSK);
  float* kapS = (float*)(smem + ALDS_KAP);
  float* pS   = (float*)(smem + ALDS_P);
  float* ppsS = (float*)(smem + ALDS_PPS);
  const int tid = threadIdx.x;
  const int b0 = j2*2;
  for (int i = tid; i < 2*80*128; i += 256) {
    int bi = i/10240, rem = i%10240;
    ctxS[i] = ctx[(size_t)(b0+bi)*10240 + rem];
  }
  for (int i = tid; i < 30*400; i += 256) {
    int row = i/400, k = i - row*400;
    atwS[row*401 + k] = attnW[i];
  }
  for (int i = tid; i < 160; i += 256) {
    int bi = i/80, u = i - bi*80;
    mskS[i] = cmask[(b0+bi)*80 + u];
  }
  if (tid < 20) kapS[tid] = 0.f;
  float aB = (tid < 60) ? attnB[tid % 30] : 0.f;
  __syncthreads();

  for (int t = 1; t <= TD; ++t) {
    if ((tid>>6) == 0) waitflags2(fA, NBL, (unsigned)t, nullptr, 0, 0u);
    __syncthreads();
    if (tid < 200) {
      int bi = tid/100, k = (tid%100)*4;
      size_t off = ((size_t)t*B_ + (b0+bi))*HP + k;
      u16x4 hi4 = *(const u16x4*)(hb0 + off);
      u16x4 lo4 = *(const u16x4*)(hlo_ + off);
      #pragma unroll
      for (int e=0;e<4;++e) hS[bi*400 + k + e] = b2f(hi4[e]) + b2f(lo4[e]);
    }
    __syncthreads();
    if (tid < 240) {
      int bi = tid/120, r = tid - bi*120;
      int row = r>>2, seg = r&3;
      const float* ar = atwS + row*401 + seg*100;
      const float* hr = hS + bi*400 + seg*100;
      float a0=0,a1=0,a2=0,a3=0;
      #pragma unroll 4
      for (int k=0;k<100;k+=4){
        a0 += ar[k]*hr[k]; a1 += ar[k+1]*hr[k+1];
        a2 += ar[k+2]*hr[k+2]; a3 += ar[k+3]*hr[k+3];
      }
      ppsS[(bi*30+row)*4+seg] = a0+a1+a2+a3;
    }
    __syncthreads();
    if (tid < 60) {
      int bi = tid/30, row = tid - bi*30;
      const float* pp = ppsS + (bi*30+row)*4;
      pS[bi*30+row] = __expf(pp[0]+pp[1]+pp[2]+pp[3] + aB);
    }
    __syncthreads();
    if (tid < 20) {
      int bi = tid/10, m = tid - bi*10;
      kapS[tid] += 0.2f * pS[bi*30 + 20 + m];
    }
    __syncthreads();
    if (tid < 160) {
      int bi = tid/80; float u2 = (float)(tid - bi*80);
      const float* pb = pS + bi*30; const float* kb = kapS + bi*10;
      float a = 0.f;
      #pragma unroll
      for (int m=0;m<10;++m){ float d = kb[m]-u2; a += pb[m]*__expf(-pb[10+m]*d*d); }
      phiS[tid] = a * mskS[tid];
    }
    __syncthreads();
    {
      int bi = tid >> 7, e = tid & 127;
      const float* ph = phiS + bi*80;
      const float* cs = ctxS + (size_t)bi*10240 + e;
      float a = 0.f;
      for (int u = 0; u < TC; ++u) a += ph[u]*cs[u*128];
      st16(wbf + ((size_t)(t-1)*B_ + (b0+bi))*ENC + e, f2b(a));
    }
    __syncthreads();
    if (tid == 0) setflag(fB + (size_t)j2*CSTR, (unsigned)t);
  }
}

// ---------------- xcc uniformity check (per LSTM stage) ----------------
DI bool xcc_check(char* smem, int stage, int j, unsigned* xccb){
  unsigned* xs = xccb + (size_t)stage*FSLOT*CSTR;
  if (threadIdx.x == 0) setflag(xs + (size_t)j*CSTR, 0x100u | (unsigned)get_xcc());
  if ((threadIdx.x>>6) == 0) {
    waitflags2(xs, NBL, 0x100u, nullptr, 0, 0u);
    int lane = threadIdx.x & 63;
    unsigned v = __hip_atomic_load(xs + (size_t)((lane<NBL)?lane:0)*CSTR,
                                   __ATOMIC_RELAXED, __HIP_MEMORY_SCOPE_AGENT);
    unsigned r0 = __shfl(v, 0);
    int uni = __all(v == r0) ? 1 : 0;
    if (threadIdx.x == 0) *(int*)(smem + LDS_VERD) = uni;
  }
  __syncthreads();
  return (*(int*)(smem + LDS_VERD)) != 0;
}

// ---------------- mega kernel (grid 256: role by b%8 column) ----------------
__global__ __launch_bounds__(256,1) void k_mega(
    const u16* apkH, const u16* apkL, const u16* wf1, const u16* wf2,
    const float* strokesT, const float* Wih0, const float* Wih1, const float* Wih2,
    const float* bia, const float* h0g,
    u16* hb0, u16* hb1, u16* hb2, u16* hlo, u16* wbf,
    const float* ctx, const float* cmask, const float* attnW, const float* attnB,
    unsigned* cnt, unsigned* xccb, unsigned* flgb,
    u16* hl0, u16* ll0, u16* hl1, u16* hl2)
{
  extern __shared__ char smem[];
  unsigned* fA = cnt;
  unsigned* fB = cnt + (size_t)FSLOT*CSTR;
  unsigned* fC = cnt + (size_t)2*FSLOT*CSTR;
  unsigned* fD = cnt + (size_t)3*FSLOT*CSTR;
  int b = blockIdx.x; int colx = b & 7; int row = b >> 3;
  if (colx == 0 && row < NBL) {
    bool loc = xcc_check(smem, 0, row, xccb);
    if (loc) stage_lstm<0,true >(smem, row, apkH, apkL, strokesT, Wih0, 3, bia, h0g,
                  hb0, nullptr, hlo, nullptr, fA, nullptr, 0, hl0, ll0, flgb);
    else     stage_lstm<0,false>(smem, row, apkH, apkL, strokesT, Wih0, 3, bia, h0g,
                  hb0, nullptr, hlo, nullptr, fA, nullptr, 0, hl0, ll0, flgb);
  } else if ((colx == 1 || colx == 2) && row < 16) {
    int j2 = (colx-1)*16 + row;
    stage_attn(smem, j2, ctx, cmask, attnW, attnB, hb0, hlo, wbf, fA, fB);
  } else if (colx == 3 && row < NBL) {
    bool loc = xcc_check(smem, 1, row, xccb);
    unsigned* fg = flgb + (size_t)FSLOT*CSTR;
    if (loc) stage_lstm<1,true >(smem, row, apkH + (size_t)1*NBL*26624, wf1, strokesT, Wih1, 531,
                  bia+1600, h0g, hb1, hb0, nullptr, wbf, fC, fB, NBA, hl1, nullptr, fg);
    else     stage_lstm<1,false>(smem, row, apkH + (size_t)1*NBL*26624, wf1, strokesT, Wih1, 531,
                  bia+1600, h0g, hb1, hb0, nullptr, wbf, fC, fB, NBA, hl1, nullptr, fg);
  } else if (colx == 4 && row < NBL) {
    bool loc = xcc_check(smem, 2, row, xccb);
    unsigned* fg = flgb + (size_t)2*FSLOT*CSTR;
    if (loc) stage_lstm<2,true >(smem, row, apkH + (size_t)2*NBL*26624, wf2, strokesT, Wih2, 531,
                  bia+3200, h0g, hb2, hb1, nullptr, wbf, fD, fC, NBL, hl2, nullptr, fg);
    else     stage_lstm<2,false>(smem, row, apkH + (size_t)2*NBL*26624, wf2, strokesT, Wih2, 531,
                  bia+3200, h0g, hb2, hb1, nullptr, wbf, fD, fC, NBL, hl2, nullptr, fg);
  }
}

// ---------------- output projection -> f32 d_out ----------------
__global__ __launch_bounds__(256) void k_gemm_out(const u16* __restrict__ hb0, const u16* __restrict__ hb1,
                                                  const u16* __restrict__ hb2, const u16* __restrict__ ouw,
                                                  const float* __restrict__ out_b, float* __restrict__ dout){
  int wv = threadIdx.x>>6, l = threadIdx.x&63;
  int task = blockIdx.x*4 + wv;
  int ng = task & 1; int mpair = task >> 1;
  int m0 = mpair*32; int t = m0>>6; int broff = m0 & 63;
  int col = l&15, kg = l>>4;
  f32x4 acc[2][4];
  #pragma unroll
  for (int mt=0;mt<2;++mt)
    #pragma unroll
    for (int nt=0;nt<4;++nt){ f32x4 z = {0.f,0.f,0.f,0.f}; acc[mt][nt] = z; }
  for (int kt=0; kt<38; ++kt) {
    int k0 = kt*32 + kg*8;
    int reg = (k0>=800) ? 2 : ((k0>=400) ? 1 : 0);
    int koff = k0 - reg*400;
    const u16* hb = (reg==0) ? hb0 : ((reg==1) ? hb1 : hb2);
    bf16x8 afr[2];
    #pragma unroll
    for (int mt=0;mt<2;++mt)
      afr[mt] = *(const bf16x8*)(hb + ((size_t)(t+1)*B_ + broff + mt*16 + col)*HP + koff);
    #pragma unroll
    for (int nt=0;nt<4;++nt) {
      bf16x8 bfr = *(const bf16x8*)(ouw + (size_t)(ng*64 + nt*16 + col)*KOP + k0);
      #pragma unroll
      for (int mt=0;mt<2;++mt)
        acc[mt][nt] = __builtin_amdgcn_mfma_f32_16x16x32_bf16(afr[mt], bfr, acc[mt][nt], 0,0,0);
    }
  }
  #pragma unroll
  for (int mt=0;mt<2;++mt)
    #pragma unroll
    for (int nt=0;nt<4;++nt)
      #pragma unroll
      for (int r=0;r<4;++r) {
        int n = ng*64 + nt*16 + col;
        int bo = broff + mt*16 + kg*4 + r;
        if (n < OUTN) dout[((size_t)bo*TD + t)*OUTN + n] = acc[mt][nt][r] + out_b[n];
      }
}

__global__ void k_sentinel(float* o, float code){ o[threadIdx.x] = code; }

// ---------------- host ----------------
extern "C" void kernel_launch(void* const* d_in, const int* in_sizes, int n_in,
                              void* d_out, int out_size, void* d_ws, size_t ws_size,
                              hipStream_t stream) {
  const float* strokes = (const float*)d_in[0];
  const float* context = (const float*)d_in[1];
  const float* cmask   = (const float*)d_in[2];
  const float* h0      = (const float*)d_in[3];
  const float* Wih0 = (const float*)d_in[4];  const float* Whh0 = (const float*)d_in[5];
  const float* bih0 = (const float*)d_in[6];  const float* bhh0 = (const float*)d_in[7];
  const float* Wih1 = (const float*)d_in[8];  const float* Whh1 = (const float*)d_in[9];
  const float* bih1 = (const float*)d_in[10]; const float* bhh1 = (const float*)d_in[11];
  const float* Wih2 = (const float*)d_in[12]; const float* Whh2 = (const float*)d_in[13];
  const float* bih2 = (const float*)d_in[14]; const float* bhh2 = (const float*)d_in[15];
  const float* attnW = (const float*)d_in[16]; const float* attnB = (const float*)d_in[17];
  const float* outW  = (const float*)d_in[18]; const float* outB  = (const float*)d_in[19];
  float* dout = (float*)d_out;

  if (ws_size < WS_NEED) {
    float code = 1000.0f + (float)(ws_size >> 20);
    k_sentinel<<<1, 64, 0, stream>>>(dout, code);
    return;
  }

  char* ws = (char*)d_ws;
  u16* hb0 = (u16*)(ws + OFF_HB0);
  u16* hb1 = (u16*)(ws + OFF_HB1);
  u16* hb2 = (u16*)(ws + OFF_HB2);
  u16* hlo = (u16*)(ws + OFF_HLO);
  u16* wbf = (u16*)(ws + OFF_WBF);
  float* strT = (float*)(ws + OFF_STR);
  u16* apkH = (u16*)(ws + OFF_APKH);
  u16* apkL = (u16*)(ws + OFF_APKL);
  u16* wf1  = (u16*)(ws + OFF_WF1);
  u16* wf2  = (u16*)(ws + OFF_WF2);
  u16* ouw  = (u16*)(ws + OFF_OUW);
  float* bia = (float*)(ws + OFF_BIA);
  unsigned* cnt = (unsigned*)(ws + OFF_CNT);
  unsigned* xccb = (unsigned*)(ws + OFF_XCC);
  unsigned* flgb = (unsigned*)(ws + OFF_FLG);
  u16* hl0 = (u16*)(ws + OFF_HL0);
  u16* ll0 = (u16*)(ws + OFF_LL0);
  u16* hl1 = (u16*)(ws + OFF_HL1);
  u16* hl2 = (u16*)(ws + OFF_HL2);

  (void)hipFuncSetAttribute((const void*)k_mega, hipFuncAttributeMaxDynamicSharedMemorySize, LDSB);

  {
    int n = 3*B_*HP + B_*HP + 4*TD*B_*16 + 4*FSLOT + 6*FSLOT + 4*2*B_*HP;
    k_init<<<(n+255)/256, 256, 0, stream>>>(h0, hb0, hb1, hb2, hlo, cnt, xccb, flgb, hl0, ll0, hl1, hl2);
  }
  k_apack<<<(3*NBL*4*KT_H*64+255)/256, 256, 0, stream>>>(Whh0, Whh1, Whh2, apkH, apkL);
  k_wihpack2<<<(NBL*4*17*64+255)/256, 256, 0, stream>>>(Wih1, wf1);
  k_wihpack2<<<(NBL*4*17*64+255)/256, 256, 0, stream>>>(Wih2, wf2);
  {
    int n = NOP*KOP + 3*1600;
    k_smallpack<<<(n+255)/256, 256, 0, stream>>>(outW, bih0,bhh0,bih1,bhh1,bih2,bhh2, ouw, bia);
  }
  k_packs<<<(TD*B_+255)/256, 256, 0, stream>>>(strokes, strT);

  // ---- fused pipelined recurrence (256-block grid, XCD-column layout) ----
  k_mega<<<256, 256, LDSB, stream>>>(apkH, apkL, wf1, wf2,
      strT, Wih0, Wih1, Wih2, bia, h0,
      hb0, hb1, hb2, hlo, wbf,
      context, cmask, attnW, attnB, cnt, xccb, flgb, hl0, ll0, hl1, hl2);

  // ---- output projection ----
  k_gemm_out<<<3200/4, 256, 0, stream>>>(hb0, hb1, hb2, ouw, outB, dout);
}